// Round 5
// baseline (2154.502 us; speedup 1.0000x reference)
//
#include <hip/hip_runtime.h>
#include <hip/hip_bf16.h>

// ---------- helpers ----------
__device__ __forceinline__ unsigned encf(float f) {
  unsigned u = __float_as_uint(f);
  return (u & 0x80000000u) ? ~u : (u | 0x80000000u);
}
__device__ __forceinline__ float decf(unsigned u) {
  unsigned b = (u & 0x80000000u) ? (u & 0x7fffffffu) : ~u;
  return __uint_as_float(b);
}

// ---------- generic tiled SGEMM with bias: C[Nr,Dout] = A[Nr,K] @ W[K,Dout] + b ----------
template<int BM, int BN, int BK>
__global__ __launch_bounds__(256) void sgemm_bias(
    const float* __restrict__ A, const float* __restrict__ W,
    const float* __restrict__ bias, float* __restrict__ C,
    int Nr, int K, int Dout)
{
  __shared__ float As[BK][BM];   // As[k][m]
  __shared__ float Ws[BK][BN];   // Ws[k][n]
  const int t  = threadIdx.x;
  const int tx = t & 15;         // 16 cols-groups
  const int ty = t >> 4;         // 16 row-groups
  const int row0 = blockIdx.x * BM;
  const int col0 = blockIdx.y * BN;
  float acc[4][4] = {};
  for (int kb = 0; kb < K; kb += BK) {
    {
      int m  = t >> 2;
      int kq = (t & 3) * 8;
      int r  = row0 + m;
      float4 a0, a1;
      if (r < Nr) {
        const float* p = A + (long long)r * K + kb + kq;
        a0 = *(const float4*)p;
        a1 = *(const float4*)(p + 4);
      } else {
        a0 = make_float4(0.f,0.f,0.f,0.f); a1 = a0;
      }
      As[kq+0][m]=a0.x; As[kq+1][m]=a0.y; As[kq+2][m]=a0.z; As[kq+3][m]=a0.w;
      As[kq+4][m]=a1.x; As[kq+5][m]=a1.y; As[kq+6][m]=a1.z; As[kq+7][m]=a1.w;
    }
    {
      int cw = tx * 4;
#pragma unroll
      for (int it = 0; it < 2; ++it) {
        int kw = ty + it * 16;
        float4 w4 = *(const float4*)(W + (long long)(kb + kw) * Dout + col0 + cw);
        *(float4*)&Ws[kw][cw] = w4;
      }
    }
    __syncthreads();
#pragma unroll
    for (int kk = 0; kk < BK; ++kk) {
      float4 a4 = *(const float4*)&As[kk][ty * 4];
      float4 b4 = *(const float4*)&Ws[kk][tx * 4];
      float av[4] = {a4.x, a4.y, a4.z, a4.w};
      float bv[4] = {b4.x, b4.y, b4.z, b4.w};
#pragma unroll
      for (int i = 0; i < 4; ++i)
#pragma unroll
        for (int j = 0; j < 4; ++j)
          acc[i][j] += av[i] * bv[j];
    }
    __syncthreads();
  }
  float4 bb = *(const float4*)(bias + col0 + tx * 4);
  float bv4[4] = {bb.x, bb.y, bb.z, bb.w};
#pragma unroll
  for (int i = 0; i < 4; ++i) {
    int r = row0 + ty * 4 + i;
    if (r < Nr) {
      float4 o;
      o.x = acc[i][0] + bv4[0];
      o.y = acc[i][1] + bv4[1];
      o.z = acc[i][2] + bv4[2];
      o.w = acc[i][3] + bv4[3];
      *(float4*)(C + (long long)r * Dout + col0 + tx * 4) = o;
    }
  }
}

// ---------- edge score: score[e,h] = q[dst]·k[src]/sqrt(DH), atomicMax per (dst,h) ----------
template<int H, int DH>
__global__ __launch_bounds__(256) void edge_score(
    const int* __restrict__ ei, const float* __restrict__ q, const float* __restrict__ k,
    float* __restrict__ score, unsigned* __restrict__ mEnc, int E)
{
  constexpr int D   = H * DH;
  constexpr int LP  = D / 4;     // lanes per edge
  constexpr int EPW = 64 / LP;   // edges per wave
  int lane = threadIdx.x & 63;
  long long wid = ((long long)blockIdx.x * blockDim.x + threadIdx.x) >> 6;
  int sub = lane / LP;
  int r   = lane % LP;
  long long e = wid * EPW + sub;
  if (e >= E) return;
  int s = ei[e], d = ei[E + e];
  int h = r / (DH / 4);
  float4 qv = *(const float4*)(q + (long long)d * D + r * 4);
  float4 kv = *(const float4*)(k + (long long)s * D + r * 4);
  float acc = qv.x * kv.x + qv.y * kv.y + qv.z * kv.z + qv.w * kv.w;
#pragma unroll
  for (int off = DH / 8; off >= 1; off >>= 1)
    acc += __shfl_xor(acc, off, 64);
  if ((r & (DH / 4 - 1)) == 0) {
    float sc = acc * (1.0f / sqrtf((float)DH));
    score[e * H + h] = sc;
    atomicMax(mEnc + (long long)d * H + h, encf(sc));
  }
}

// ---------- edge aggregate: p=exp(s-m); denom += p; o[dst] += p*v[src] ----------
template<int H, int DH>
__global__ __launch_bounds__(256) void edge_agg(
    const int* __restrict__ ei, const float* __restrict__ v,
    const float* __restrict__ score, const unsigned* __restrict__ mEnc,
    float* __restrict__ denom, float* __restrict__ o, int E)
{
  constexpr int D   = H * DH;
  constexpr int LP  = D / 4;
  constexpr int EPW = 64 / LP;
  int lane = threadIdx.x & 63;
  long long wid = ((long long)blockIdx.x * blockDim.x + threadIdx.x) >> 6;
  int sub = lane / LP;
  int r   = lane % LP;
  long long e = wid * EPW + sub;
  if (e >= E) return;
  int s = ei[e], d = ei[E + e];
  int h = r / (DH / 4);
  float m = decf(mEnc[(long long)d * H + h]);
  float p = expf(score[e * H + h] - m);
  if ((r & (DH / 4 - 1)) == 0)
    atomicAdd(denom + (long long)d * H + h, p);
  float4 vv = *(const float4*)(v + (long long)s * D + r * 4);
  float* dp = o + (long long)d * D + r * 4;
  atomicAdd(dp + 0, p * vv.x);
  atomicAdd(dp + 1, p * vv.y);
  atomicAdd(dp + 2, p * vv.z);
  atomicAdd(dp + 3, p * vv.w);
}

// ---------- node: normalize, beta-gate, BN(eval), ELU ----------
template<int D, int H>
__global__ __launch_bounds__(256) void node_gate(
    const float* __restrict__ o, const float* __restrict__ denom,
    const float* __restrict__ xr, const float* __restrict__ Wb,
    const float* __restrict__ g, const float* __restrict__ be,
    const float* __restrict__ bm, const float* __restrict__ bv,
    float* __restrict__ out, int N)
{
  constexpr int DH  = D / H;
  constexpr int PER = D / 64;   // 4 (D=256) or 2 (D=128)
  int node = blockIdx.x * (blockDim.x >> 6) + (threadIdx.x >> 6);
  if (node >= N) return;
  int lane = threadIdx.x & 63;
  int j0   = lane * PER;
  float dn = denom[(long long)node * H + j0 / DH] + 1e-16f;
  float ov[PER], xv[PER];
  if constexpr (PER == 4) {
    float4 o4 = *(const float4*)(o  + (long long)node * D + j0);
    float4 x4 = *(const float4*)(xr + (long long)node * D + j0);
    ov[0]=o4.x; ov[1]=o4.y; ov[2]=o4.z; ov[3]=o4.w;
    xv[0]=x4.x; xv[1]=x4.y; xv[2]=x4.z; xv[3]=x4.w;
  } else {
    float2 o2 = *(const float2*)(o  + (long long)node * D + j0);
    float2 x2 = *(const float2*)(xr + (long long)node * D + j0);
    ov[0]=o2.x; ov[1]=o2.y;
    xv[0]=x2.x; xv[1]=x2.y;
  }
  float dot = 0.f;
#pragma unroll
  for (int i = 0; i < PER; ++i) {
    int j = j0 + i;
    ov[i] = ov[i] / dn;
    dot += ov[i] * Wb[j] + xv[i] * Wb[D + j] + (ov[i] - xv[i]) * Wb[2 * D + j];
  }
#pragma unroll
  for (int off = 32; off >= 1; off >>= 1) dot += __shfl_xor(dot, off, 64);
  float beta = 1.f / (1.f + expf(-dot));
  float res[PER];
#pragma unroll
  for (int i = 0; i < PER; ++i) {
    int j = j0 + i;
    float h = beta * xv[i] + (1.f - beta) * ov[i];
    float y = (h - bm[j]) * rsqrtf(bv[j] + 1e-5f) * g[j] + be[j];
    res[i] = y > 0.f ? y : expf(y) - 1.f;
  }
  if constexpr (PER == 4) {
    float4 w; w.x=res[0]; w.y=res[1]; w.z=res[2]; w.w=res[3];
    *(float4*)(out + (long long)node * D + j0) = w;
  } else {
    float2 w; w.x=res[0]; w.y=res[1];
    *(float2*)(out + (long long)node * D + j0) = w;
  }
}

// ---------- loss: pos/neg BCE over edge dot products of z (D=128) ----------
__global__ __launch_bounds__(256) void loss_kernel(
    const int* __restrict__ ei, const int* __restrict__ nei,
    const float* __restrict__ z, int E, float* __restrict__ acc)
{
  int lane = threadIdx.x & 63;
  int wib  = threadIdx.x >> 6;
  int sub  = lane >> 5, r = lane & 31;
  long long gw = ((long long)blockIdx.x * blockDim.x + threadIdx.x) >> 6;
  long long nw = ((long long)gridDim.x * blockDim.x) >> 6;
  float lpos = 0.f, lneg = 0.f;
  for (long long w = gw * 2 + sub; w < 2LL * E; w += nw * 2) {
    int isneg = (w >= E);
    const int* ep = isneg ? nei : ei;
    long long idx = isneg ? w - E : w;
    int s = ep[idx], d = ep[E + idx];
    float4 a = *(const float4*)(z + (long long)s * 128 + r * 4);
    float4 b = *(const float4*)(z + (long long)d * 128 + r * 4);
    float dot = a.x * b.x + a.y * b.y + a.z * b.z + a.w * b.w;
#pragma unroll
    for (int off = 16; off >= 1; off >>= 1) dot += __shfl_xor(dot, off, 64);
    if (r == 0) {
      float sg = 1.f / (1.f + expf(-dot));
      if (isneg) lneg += -logf(1.f - sg + 1e-15f);
      else       lpos += -logf(sg + 1e-15f);
    }
  }
#pragma unroll
  for (int off = 32; off >= 1; off >>= 1) {
    lpos += __shfl_xor(lpos, off, 64);
    lneg += __shfl_xor(lneg, off, 64);
  }
  __shared__ float sp[4], sn[4];
  if (lane == 0) { sp[wib] = lpos; sn[wib] = lneg; }
  __syncthreads();
  if (threadIdx.x == 0) {
    float P = 0.f, Ng = 0.f;
    for (int i = 0; i < 4; ++i) { P += sp[i]; Ng += sn[i]; }
    atomicAdd(acc, P);
    atomicAdd(acc + 1, Ng);
  }
}

// ---------- conv3: fused 4-way GEMV (D2=128 -> 1) ----------
__global__ __launch_bounds__(256) void gemv4(
    const float* __restrict__ z,
    const float* __restrict__ Wq, const float* __restrict__ bq,
    const float* __restrict__ Wk, const float* __restrict__ bk,
    const float* __restrict__ Wv, const float* __restrict__ bv,
    const float* __restrict__ Ws, const float* __restrict__ bs,
    float* __restrict__ q3, float* __restrict__ k3,
    float* __restrict__ v3, float* __restrict__ s3, int N)
{
  int node = blockIdx.x * (blockDim.x >> 6) + (threadIdx.x >> 6);
  if (node >= N) return;
  int lane = threadIdx.x & 63;
  float2 zv = *(const float2*)(z + (long long)node * 128 + lane * 2);
  float aq = zv.x * Wq[lane*2] + zv.y * Wq[lane*2+1];
  float ak = zv.x * Wk[lane*2] + zv.y * Wk[lane*2+1];
  float av = zv.x * Wv[lane*2] + zv.y * Wv[lane*2+1];
  float as_ = zv.x * Ws[lane*2] + zv.y * Ws[lane*2+1];
#pragma unroll
  for (int off = 32; off >= 1; off >>= 1) {
    aq  += __shfl_xor(aq,  off, 64);
    ak  += __shfl_xor(ak,  off, 64);
    av  += __shfl_xor(av,  off, 64);
    as_ += __shfl_xor(as_, off, 64);
  }
  if (lane == 0) {
    q3[node] = aq + bq[0];
    k3[node] = ak + bk[0];
    v3[node] = av + bv[0];
    s3[node] = as_ + bs[0];
  }
}

__global__ __launch_bounds__(256) void edge3_score(
    const int* __restrict__ ei, const float* __restrict__ q3, const float* __restrict__ k3,
    float* __restrict__ score, unsigned* __restrict__ mEnc, int E)
{
  long long e = (long long)blockIdx.x * blockDim.x + threadIdx.x;
  if (e >= E) return;
  int s = ei[e], d = ei[E + e];
  float sc = q3[d] * k3[s];
  score[e] = sc;
  atomicMax(mEnc + d, encf(sc));
}

__global__ __launch_bounds__(256) void edge3_agg(
    const int* __restrict__ ei, const float* __restrict__ v3, const float* __restrict__ score,
    const unsigned* __restrict__ mEnc, float* __restrict__ den, float* __restrict__ o, int E)
{
  long long e = (long long)blockIdx.x * blockDim.x + threadIdx.x;
  if (e >= E) return;
  int s = ei[e], d = ei[E + e];
  float p = expf(score[e] - decf(mEnc[d]));
  atomicAdd(den + d, p);
  atomicAdd(o + d, p * v3[s]);
}

__global__ __launch_bounds__(256) void node3_final(
    const float* __restrict__ o, const float* __restrict__ den, const float* __restrict__ s3,
    const float* __restrict__ Wb3, float* __restrict__ out, int N)
{
  int n = blockIdx.x * blockDim.x + threadIdx.x;
  if (n >= N) return;
  float on = o[n] / (den[n] + 1e-16f);
  float xr = s3[n];
  float tv = on * Wb3[0] + xr * Wb3[1] + (on - xr) * Wb3[2];
  float b = 1.f / (1.f + expf(-tv));
  out[n] = b * xr + (1.f - b) * on;
}

__global__ void finalize_kernel(const float* __restrict__ acc,
                                const float* __restrict__ c1, const float* __restrict__ c2,
                                float* __restrict__ out, int N, int E)
{
  out[N]     = acc[0] / (float)E + acc[1] / (float)E;
  out[N + 1] = c1[0];
  out[N + 2] = c2[0];
}

// ---------- orchestration ----------
extern "C" void kernel_launch(void* const* d_in, const int* in_sizes, int n_in,
                              void* d_out, int out_size, void* d_ws, size_t ws_size,
                              hipStream_t stream)
{
  const float* x   = (const float*)d_in[0];
  const int*   ei  = (const int*)d_in[1];
  const int*   nei = (const int*)d_in[2];
  const float* Wq1 = (const float*)d_in[3];  const float* bq1 = (const float*)d_in[4];
  const float* Wk1 = (const float*)d_in[5];  const float* bk1 = (const float*)d_in[6];
  const float* Wv1 = (const float*)d_in[7];  const float* bv1 = (const float*)d_in[8];
  const float* Ws1 = (const float*)d_in[9];  const float* bs1 = (const float*)d_in[10];
  const float* Wb1 = (const float*)d_in[11];
  const float* g1  = (const float*)d_in[12]; const float* be1 = (const float*)d_in[13];
  const float* m1  = (const float*)d_in[14]; const float* v1  = (const float*)d_in[15];
  const float* Wq2 = (const float*)d_in[16]; const float* bq2 = (const float*)d_in[17];
  const float* Wk2 = (const float*)d_in[18]; const float* bk2 = (const float*)d_in[19];
  const float* Wv2 = (const float*)d_in[20]; const float* bv2 = (const float*)d_in[21];
  const float* Ws2 = (const float*)d_in[22]; const float* bs2 = (const float*)d_in[23];
  const float* Wb2 = (const float*)d_in[24];
  const float* g2  = (const float*)d_in[25]; const float* be2 = (const float*)d_in[26];
  const float* m2  = (const float*)d_in[27]; const float* v2  = (const float*)d_in[28];
  const float* Wq3 = (const float*)d_in[29]; const float* bq3 = (const float*)d_in[30];
  const float* Wk3 = (const float*)d_in[31]; const float* bk3 = (const float*)d_in[32];
  const float* Wv3 = (const float*)d_in[33]; const float* bv3 = (const float*)d_in[34];
  const float* Ws3 = (const float*)d_in[35]; const float* bs3 = (const float*)d_in[36];
  const float* Wb3 = (const float*)d_in[37];
  const float* c1  = (const float*)d_in[38]; const float* c2  = (const float*)d_in[39];

  const int N = in_sizes[0] / 128;   // 50000
  const int E = in_sizes[1] / 2;     // 250000

  float* ws = (float*)d_ws;
  float* B0    = ws;                              // N*256
  float* B1    = B0 + (size_t)N * 256;            // N*256
  float* B2    = B1 + (size_t)N * 256;            // N*256
  float* score = B2 + (size_t)N * 256;            // E*4
  float* denom = score + (size_t)E * 4;           // N*4
  unsigned* mEnc = (unsigned*)(denom + (size_t)N * 4); // N*4
  float* acc   = (float*)(mEnc + (size_t)N * 4);  // 2

  size_t need = ((size_t)3 * N * 256 + (size_t)E * 4 + (size_t)N * 8 + 2) * 4;
  if (ws_size < need) return;

  float* out = (float*)d_out;
  dim3 blk(256);
  dim3 gemm1g((N + 63) / 64, 256 / 64);
  dim3 gemm2g((N + 63) / 64, 128 / 64);
  int eb1 = (E + 3) / 4;   // conv1 edge kernels: 4 edges/block
  int eb2 = (E + 7) / 8;   // conv2 edge kernels: 8 edges/block
  int ng  = (N + 3) / 4;   // node kernels: 4 nodes/block

  // ================= conv1 =================
  sgemm_bias<64,64,32><<<gemm1g, blk, 0, stream>>>(x, Wq1, bq1, B0, N, 128, 256);
  sgemm_bias<64,64,32><<<gemm1g, blk, 0, stream>>>(x, Wk1, bk1, B1, N, 128, 256);
  hipMemsetAsync(mEnc,  0, (size_t)N * 4 * sizeof(unsigned), stream);
  hipMemsetAsync(denom, 0, (size_t)N * 4 * sizeof(float), stream);
  edge_score<4,64><<<eb1, blk, 0, stream>>>(ei, B0, B1, score, mEnc, E);
  sgemm_bias<64,64,32><<<gemm1g, blk, 0, stream>>>(x, Wv1, bv1, B0, N, 128, 256);
  sgemm_bias<64,64,32><<<gemm1g, blk, 0, stream>>>(x, Ws1, bs1, B1, N, 128, 256);
  hipMemsetAsync(B2, 0, (size_t)N * 256 * sizeof(float), stream);
  edge_agg<4,64><<<eb1, blk, 0, stream>>>(ei, B0, score, mEnc, denom, B2, E);
  // h -> B0
  node_gate<256,4><<<ng, blk, 0, stream>>>(B2, denom, B1, Wb1, g1, be1, m1, v1, B0, N);

  // ================= conv2 (input h = B0) =================
  sgemm_bias<64,64,32><<<gemm2g, blk, 0, stream>>>(B0, Wq2, bq2, B1, N, 256, 128);
  sgemm_bias<64,64,32><<<gemm2g, blk, 0, stream>>>(B0, Wk2, bk2, B1 + (size_t)N * 128, N, 256, 128);
  hipMemsetAsync(mEnc,  0, (size_t)N * 4 * sizeof(unsigned), stream);
  hipMemsetAsync(denom, 0, (size_t)N * 4 * sizeof(float), stream);
  edge_score<4,32><<<eb2, blk, 0, stream>>>(ei, B1, B1 + (size_t)N * 128, score, mEnc, E);
  sgemm_bias<64,64,32><<<gemm2g, blk, 0, stream>>>(B0, Wv2, bv2, B2, N, 256, 128);
  sgemm_bias<64,64,32><<<gemm2g, blk, 0, stream>>>(B0, Ws2, bs2, B2 + (size_t)N * 128, N, 256, 128);
  hipMemsetAsync(B1, 0, (size_t)N * 128 * sizeof(float), stream);   // o2 = B1 (q2/k2 dead)
  edge_agg<4,32><<<eb2, blk, 0, stream>>>(ei, B2, score, mEnc, denom, B1, E);
  // z -> B0 (h dead after last gemm)
  node_gate<128,4><<<ng, blk, 0, stream>>>(B1, denom, B2 + (size_t)N * 128, Wb2, g2, be2, m2, v2, B0, N);

  // ================= loss (z = B0) =================
  hipMemsetAsync(acc, 0, 2 * sizeof(float), stream);
  loss_kernel<<<1024, blk, 0, stream>>>(ei, nei, B0, E, acc);

  // ================= conv3 (input z = B0), scratch in B1 =================
  float* q3  = B1;
  float* k3  = B1 + (size_t)N;
  float* v3  = B1 + (size_t)2 * N;
  float* s3  = B1 + (size_t)3 * N;
  float* o3  = B1 + (size_t)4 * N;
  float* den3 = B1 + (size_t)5 * N;
  unsigned* m3e = (unsigned*)(B1 + (size_t)6 * N);
  float* sc3 = B1 + (size_t)7 * N;
  gemv4<<<ng, blk, 0, stream>>>(B0, Wq3, bq3, Wk3, bk3, Wv3, bv3, Ws3, bs3, q3, k3, v3, s3, N);
  hipMemsetAsync(m3e,  0, (size_t)N * sizeof(unsigned), stream);
  hipMemsetAsync(den3, 0, (size_t)N * sizeof(float), stream);
  hipMemsetAsync(o3,   0, (size_t)N * sizeof(float), stream);
  edge3_score<<<(E + 255) / 256, blk, 0, stream>>>(ei, q3, k3, sc3, m3e, E);
  edge3_agg<<<(E + 255) / 256, blk, 0, stream>>>(ei, v3, sc3, m3e, den3, o3, E);
  node3_final<<<(N + 255) / 256, blk, 0, stream>>>(o3, den3, s3, Wb3, out, N);

  finalize_kernel<<<1, 1, 0, stream>>>(acc, c1, c2, out, N, E);
}

// Round 9
// 893.435 us; speedup vs baseline: 2.4115x; 2.4115x over previous
//
#include <hip/hip_runtime.h>
#include <hip/hip_bf16.h>

// ---------- generic tiled SGEMM with bias: C[Nr,Dout] = A[Nr,K] @ W[K,Dout] + b ----------
template<int BM, int BN, int BK>
__global__ __launch_bounds__(256) void sgemm_bias(
    const float* __restrict__ A, const float* __restrict__ W,
    const float* __restrict__ bias, float* __restrict__ C,
    int Nr, int K, int Dout)
{
  __shared__ float As[BK][BM];   // As[k][m]
  __shared__ float Ws[BK][BN];   // Ws[k][n]
  const int t  = threadIdx.x;
  const int tx = t & 15;
  const int ty = t >> 4;
  const int row0 = blockIdx.x * BM;
  const int col0 = blockIdx.y * BN;
  float acc[4][4] = {};
  for (int kb = 0; kb < K; kb += BK) {
    {
      int m  = t >> 2;
      int kq = (t & 3) * 8;
      int r  = row0 + m;
      float4 a0, a1;
      if (r < Nr) {
        const float* p = A + (long long)r * K + kb + kq;
        a0 = *(const float4*)p;
        a1 = *(const float4*)(p + 4);
      } else {
        a0 = make_float4(0.f,0.f,0.f,0.f); a1 = a0;
      }
      As[kq+0][m]=a0.x; As[kq+1][m]=a0.y; As[kq+2][m]=a0.z; As[kq+3][m]=a0.w;
      As[kq+4][m]=a1.x; As[kq+5][m]=a1.y; As[kq+6][m]=a1.z; As[kq+7][m]=a1.w;
    }
    {
      int cw = tx * 4;
#pragma unroll
      for (int it = 0; it < 2; ++it) {
        int kw = ty + it * 16;
        float4 w4 = *(const float4*)(W + (long long)(kb + kw) * Dout + col0 + cw);
        *(float4*)&Ws[kw][cw] = w4;
      }
    }
    __syncthreads();
#pragma unroll
    for (int kk = 0; kk < BK; ++kk) {
      float4 a4 = *(const float4*)&As[kk][ty * 4];
      float4 b4 = *(const float4*)&Ws[kk][tx * 4];
      float av[4] = {a4.x, a4.y, a4.z, a4.w};
      float bv[4] = {b4.x, b4.y, b4.z, b4.w};
#pragma unroll
      for (int i = 0; i < 4; ++i)
#pragma unroll
        for (int j = 0; j < 4; ++j)
          acc[i][j] += av[i] * bv[j];
    }
    __syncthreads();
  }
  float4 bb = *(const float4*)(bias + col0 + tx * 4);
  float bv4[4] = {bb.x, bb.y, bb.z, bb.w};
#pragma unroll
  for (int i = 0; i < 4; ++i) {
    int r = row0 + ty * 4 + i;
    if (r < Nr) {
      float4 o;
      o.x = acc[i][0] + bv4[0];
      o.y = acc[i][1] + bv4[1];
      o.z = acc[i][2] + bv4[2];
      o.w = acc[i][3] + bv4[3];
      *(float4*)(C + (long long)r * Dout + col0 + tx * 4) = o;
    }
  }
}

// ================= CSR build (dst-indexed), reused by all 3 convs =================
__global__ __launch_bounds__(256) void csr_hist(
    const int* __restrict__ ei, int E, int* __restrict__ cnt)
{
  int e = blockIdx.x * 256 + threadIdx.x;
  if (e >= E) return;
  atomicAdd(&cnt[ei[E + e]], 1);
}

// two-level exclusive scan; CH=1024 elems/block, 256 thr x 4
__global__ __launch_bounds__(256) void csr_scan1(
    const int* __restrict__ cnt, int* __restrict__ excl,
    int* __restrict__ chunkSums, int N)
{
  int b = blockIdx.x, t = threadIdx.x;
  int lane = t & 63, w = t >> 6;
  int base = b * 1024 + t * 4;
  int c[4];
#pragma unroll
  for (int j = 0; j < 4; ++j) c[j] = (base + j < N) ? cnt[base + j] : 0;
  int ts = c[0] + c[1] + c[2] + c[3];
  int s = ts;
#pragma unroll
  for (int d = 1; d < 64; d <<= 1) {
    int u = __shfl_up(s, d, 64);
    if (lane >= d) s += u;
  }
  __shared__ int wsum[4];
  if (lane == 63) wsum[w] = s;
  __syncthreads();
  int woff = 0;
  for (int i = 0; i < w; ++i) woff += wsum[i];
  int off = woff + s - ts;          // exclusive offset for this thread
#pragma unroll
  for (int j = 0; j < 4; ++j) {
    if (base + j < N) excl[base + j] = off;
    off += c[j];
  }
  if (t == 0) chunkSums[b] = wsum[0] + wsum[1] + wsum[2] + wsum[3];
}

// nch <= 64 required (N=50000 -> nch=49)
__global__ void csr_scan2(int* __restrict__ chunkSums, int nch,
                          int* __restrict__ rowptr, int N, int E)
{
  int lane = threadIdx.x;
  int v = (lane < nch) ? chunkSums[lane] : 0;
  int s = v;
#pragma unroll
  for (int d = 1; d < 64; d <<= 1) {
    int u = __shfl_up(s, d, 64);
    if (lane >= d) s += u;
  }
  if (lane < nch) chunkSums[lane] = s - v;   // exclusive
  if (lane == 0) rowptr[N] = E;
}

__global__ __launch_bounds__(256) void csr_scan3(
    int* __restrict__ rowptr, const int* __restrict__ chunkSums, int N)
{
  int i = blockIdx.x * 256 + threadIdx.x;
  if (i < N) rowptr[i] += chunkSums[i >> 10];
}

__global__ __launch_bounds__(256) void csr_scatter(
    const int* __restrict__ ei, int E, const int* __restrict__ rowptr,
    int* __restrict__ fill, int* __restrict__ csr_src)
{
  int e = blockIdx.x * 256 + threadIdx.x;
  if (e >= E) return;
  int s = ei[e], d = ei[E + e];
  int pos = atomicAdd(&fill[d], 1);
  csr_src[rowptr[d] + pos] = s;
}

// ================= fused per-node online-softmax attention =================
// one wave per dst node; writes NORMALIZED output row (o may alias q: each
// wave reads only q[own node] and writes o[own node] last).
template<int D, int H>
__global__ __launch_bounds__(256) void attn_fused(
    const int* __restrict__ rowptr, const int* __restrict__ csr_src,
    const float* __restrict__ q, const float* __restrict__ k,
    const float* __restrict__ v, float* __restrict__ o, int N)
{
  constexpr int PER = D / 64;     // 4 (D=256) or 2 (D=128)
  constexpr int DH  = D / H;      // 64 or 32 dims per head; 16 lanes per head
  int node = blockIdx.x * 4 + (threadIdx.x >> 6);
  if (node >= N) return;
  int lane = threadIdx.x & 63;
  int j0   = lane * PER;
  const float inv = 1.0f / sqrtf((float)DH);

  float qv[PER];
  if constexpr (PER == 4) {
    float4 t4 = *(const float4*)(q + (long long)node * D + j0);
    qv[0]=t4.x; qv[1]=t4.y; qv[2]=t4.z; qv[3]=t4.w;
  } else {
    float2 t2 = *(const float2*)(q + (long long)node * D + j0);
    qv[0]=t2.x; qv[1]=t2.y;
  }

  float m = -INFINITY, den = 0.f;
  float acc[PER] = {};
  int beg = rowptr[node], end = rowptr[node + 1];
  for (int i = beg; i < end; ++i) {
    int s = csr_src[i];
    float kv[PER], vv[PER];
    if constexpr (PER == 4) {
      float4 t4 = *(const float4*)(k + (long long)s * D + j0);
      kv[0]=t4.x; kv[1]=t4.y; kv[2]=t4.z; kv[3]=t4.w;
      float4 u4 = *(const float4*)(v + (long long)s * D + j0);
      vv[0]=u4.x; vv[1]=u4.y; vv[2]=u4.z; vv[3]=u4.w;
    } else {
      float2 t2 = *(const float2*)(k + (long long)s * D + j0);
      kv[0]=t2.x; kv[1]=t2.y;
      float2 u2 = *(const float2*)(v + (long long)s * D + j0);
      vv[0]=u2.x; vv[1]=u2.y;
    }
    float dot = 0.f;
#pragma unroll
    for (int j = 0; j < PER; ++j) dot += qv[j] * kv[j];
    dot += __shfl_xor(dot, 8, 64);   // reduce within the 16-lane head group
    dot += __shfl_xor(dot, 4, 64);
    dot += __shfl_xor(dot, 2, 64);
    dot += __shfl_xor(dot, 1, 64);
    float score = dot * inv;
    float nm = fmaxf(m, score);
    float scale = __expf(m - nm);     // exp(-inf)=0 on first neighbor
    float p = __expf(score - nm);
    den = den * scale + p;
#pragma unroll
    for (int j = 0; j < PER; ++j) acc[j] = acc[j] * scale + p * vv[j];
    m = nm;
  }
  float r = 1.f / (den + 1e-16f);
  if constexpr (PER == 4) {
    float4 w4; w4.x = acc[0]*r; w4.y = acc[1]*r; w4.z = acc[2]*r; w4.w = acc[3]*r;
    *(float4*)(o + (long long)node * D + j0) = w4;
  } else {
    float2 w2; w2.x = acc[0]*r; w2.y = acc[1]*r;
    *(float2*)(o + (long long)node * D + j0) = w2;
  }
}

// ---------- node: beta-gate, BN(eval), ELU (o is pre-normalized) ----------
template<int D>
__global__ __launch_bounds__(256) void node_gate2(
    const float* __restrict__ o, const float* __restrict__ xr,
    const float* __restrict__ Wb, const float* __restrict__ g,
    const float* __restrict__ be, const float* __restrict__ bm,
    const float* __restrict__ bv, float* __restrict__ out, int N)
{
  constexpr int PER = D / 64;
  int node = blockIdx.x * 4 + (threadIdx.x >> 6);
  if (node >= N) return;
  int lane = threadIdx.x & 63;
  int j0   = lane * PER;
  float ov[PER], xv[PER];
  if constexpr (PER == 4) {
    float4 o4 = *(const float4*)(o  + (long long)node * D + j0);
    float4 x4 = *(const float4*)(xr + (long long)node * D + j0);
    ov[0]=o4.x; ov[1]=o4.y; ov[2]=o4.z; ov[3]=o4.w;
    xv[0]=x4.x; xv[1]=x4.y; xv[2]=x4.z; xv[3]=x4.w;
  } else {
    float2 o2 = *(const float2*)(o  + (long long)node * D + j0);
    float2 x2 = *(const float2*)(xr + (long long)node * D + j0);
    ov[0]=o2.x; ov[1]=o2.y;
    xv[0]=x2.x; xv[1]=x2.y;
  }
  float dot = 0.f;
#pragma unroll
  for (int i = 0; i < PER; ++i) {
    int j = j0 + i;
    dot += ov[i] * Wb[j] + xv[i] * Wb[D + j] + (ov[i] - xv[i]) * Wb[2 * D + j];
  }
#pragma unroll
  for (int off = 32; off >= 1; off >>= 1) dot += __shfl_xor(dot, off, 64);
  float beta = 1.f / (1.f + expf(-dot));
  float res[PER];
#pragma unroll
  for (int i = 0; i < PER; ++i) {
    int j = j0 + i;
    float h = beta * xv[i] + (1.f - beta) * ov[i];
    float y = (h - bm[j]) * rsqrtf(bv[j] + 1e-5f) * g[j] + be[j];
    res[i] = y > 0.f ? y : expf(y) - 1.f;
  }
  if constexpr (PER == 4) {
    float4 w; w.x=res[0]; w.y=res[1]; w.z=res[2]; w.w=res[3];
    *(float4*)(out + (long long)node * D + j0) = w;
  } else {
    float2 w; w.x=res[0]; w.y=res[1];
    *(float2*)(out + (long long)node * D + j0) = w;
  }
}

// ---------- loss: pos/neg BCE over edge dot products of z (D=128) ----------
__global__ __launch_bounds__(256) void loss_kernel(
    const int* __restrict__ ei, const int* __restrict__ nei,
    const float* __restrict__ z, int E, float* __restrict__ acc)
{
  int lane = threadIdx.x & 63;
  int wib  = threadIdx.x >> 6;
  int sub  = lane >> 5, r = lane & 31;
  long long gw = ((long long)blockIdx.x * blockDim.x + threadIdx.x) >> 6;
  long long nw = ((long long)gridDim.x * blockDim.x) >> 6;
  float lpos = 0.f, lneg = 0.f;
  for (long long w = gw * 2 + sub; w < 2LL * E; w += nw * 2) {
    int isneg = (w >= E);
    const int* ep = isneg ? nei : ei;
    long long idx = isneg ? w - E : w;
    int s = ep[idx], d = ep[E + idx];
    float4 a = *(const float4*)(z + (long long)s * 128 + r * 4);
    float4 b = *(const float4*)(z + (long long)d * 128 + r * 4);
    float dot = a.x * b.x + a.y * b.y + a.z * b.z + a.w * b.w;
#pragma unroll
    for (int off = 16; off >= 1; off >>= 1) dot += __shfl_xor(dot, off, 64);
    if (r == 0) {
      float sg = 1.f / (1.f + expf(-dot));
      if (isneg) lneg += -logf(1.f - sg + 1e-15f);
      else       lpos += -logf(sg + 1e-15f);
    }
  }
#pragma unroll
  for (int off = 32; off >= 1; off >>= 1) {
    lpos += __shfl_xor(lpos, off, 64);
    lneg += __shfl_xor(lneg, off, 64);
  }
  __shared__ float sp[4], sn[4];
  if (lane == 0) { sp[wib] = lpos; sn[wib] = lneg; }
  __syncthreads();
  if (threadIdx.x == 0) {
    float P = 0.f, Ng = 0.f;
    for (int i = 0; i < 4; ++i) { P += sp[i]; Ng += sn[i]; }
    atomicAdd(acc, P);
    atomicAdd(acc + 1, Ng);
  }
}

// ---------- conv3: fused 4-way GEMV (D2=128 -> 1) ----------
__global__ __launch_bounds__(256) void gemv4(
    const float* __restrict__ z,
    const float* __restrict__ Wq, const float* __restrict__ bq,
    const float* __restrict__ Wk, const float* __restrict__ bk,
    const float* __restrict__ Wv, const float* __restrict__ bv,
    const float* __restrict__ Ws, const float* __restrict__ bs,
    float* __restrict__ q3, float* __restrict__ k3,
    float* __restrict__ v3, float* __restrict__ s3, int N)
{
  int node = blockIdx.x * 4 + (threadIdx.x >> 6);
  if (node >= N) return;
  int lane = threadIdx.x & 63;
  float2 zv = *(const float2*)(z + (long long)node * 128 + lane * 2);
  float aq = zv.x * Wq[lane*2] + zv.y * Wq[lane*2+1];
  float ak = zv.x * Wk[lane*2] + zv.y * Wk[lane*2+1];
  float av = zv.x * Wv[lane*2] + zv.y * Wv[lane*2+1];
  float as_ = zv.x * Ws[lane*2] + zv.y * Ws[lane*2+1];
#pragma unroll
  for (int off = 32; off >= 1; off >>= 1) {
    aq  += __shfl_xor(aq,  off, 64);
    ak  += __shfl_xor(ak,  off, 64);
    av  += __shfl_xor(av,  off, 64);
    as_ += __shfl_xor(as_, off, 64);
  }
  if (lane == 0) {
    q3[node] = aq + bq[0];
    k3[node] = ak + bk[0];
    v3[node] = av + bv[0];
    s3[node] = as_ + bs[0];
  }
}

// conv3 attention + beta-gate, one thread per node (dh=1, heads=1)
__global__ __launch_bounds__(256) void attn3_node(
    const int* __restrict__ rowptr, const int* __restrict__ csr_src,
    const float* __restrict__ q3, const float* __restrict__ k3,
    const float* __restrict__ v3, const float* __restrict__ s3,
    const float* __restrict__ Wb3, float* __restrict__ out, int N)
{
  int n = blockIdx.x * 256 + threadIdx.x;
  if (n >= N) return;
  float qd = q3[n];
  float m = -INFINITY, den = 0.f, acc = 0.f;
  int beg = rowptr[n], end = rowptr[n + 1];
  for (int i = beg; i < end; ++i) {
    int s = csr_src[i];
    float sc = qd * k3[s];
    float nm = fmaxf(m, sc);
    float scale = __expf(m - nm);
    float p = __expf(sc - nm);
    den = den * scale + p;
    acc = acc * scale + p * v3[s];
    m = nm;
  }
  float on = acc / (den + 1e-16f);
  float xr = s3[n];
  float tv = on * Wb3[0] + xr * Wb3[1] + (on - xr) * Wb3[2];
  float b = 1.f / (1.f + expf(-tv));
  out[n] = b * xr + (1.f - b) * on;
}

__global__ void finalize_kernel(const float* __restrict__ acc,
                                const float* __restrict__ c1, const float* __restrict__ c2,
                                float* __restrict__ out, int N, int E)
{
  out[N]     = acc[0] / (float)E + acc[1] / (float)E;
  out[N + 1] = c1[0];
  out[N + 2] = c2[0];
}

// ---------- orchestration ----------
extern "C" void kernel_launch(void* const* d_in, const int* in_sizes, int n_in,
                              void* d_out, int out_size, void* d_ws, size_t ws_size,
                              hipStream_t stream)
{
  const float* x   = (const float*)d_in[0];
  const int*   ei  = (const int*)d_in[1];
  const int*   nei = (const int*)d_in[2];
  const float* Wq1 = (const float*)d_in[3];  const float* bq1 = (const float*)d_in[4];
  const float* Wk1 = (const float*)d_in[5];  const float* bk1 = (const float*)d_in[6];
  const float* Wv1 = (const float*)d_in[7];  const float* bv1 = (const float*)d_in[8];
  const float* Ws1 = (const float*)d_in[9];  const float* bs1 = (const float*)d_in[10];
  const float* Wb1 = (const float*)d_in[11];
  const float* g1  = (const float*)d_in[12]; const float* be1 = (const float*)d_in[13];
  const float* m1  = (const float*)d_in[14]; const float* v1  = (const float*)d_in[15];
  const float* Wq2 = (const float*)d_in[16]; const float* bq2 = (const float*)d_in[17];
  const float* Wk2 = (const float*)d_in[18]; const float* bk2 = (const float*)d_in[19];
  const float* Wv2 = (const float*)d_in[20]; const float* bv2 = (const float*)d_in[21];
  const float* Ws2 = (const float*)d_in[22]; const float* bs2 = (const float*)d_in[23];
  const float* Wb2 = (const float*)d_in[24];
  const float* g2  = (const float*)d_in[25]; const float* be2 = (const float*)d_in[26];
  const float* m2  = (const float*)d_in[27]; const float* v2  = (const float*)d_in[28];
  const float* Wq3 = (const float*)d_in[29]; const float* bq3 = (const float*)d_in[30];
  const float* Wk3 = (const float*)d_in[31]; const float* bk3 = (const float*)d_in[32];
  const float* Wv3 = (const float*)d_in[33]; const float* bv3 = (const float*)d_in[34];
  const float* Ws3 = (const float*)d_in[35]; const float* bs3 = (const float*)d_in[36];
  const float* Wb3 = (const float*)d_in[37];
  const float* c1  = (const float*)d_in[38]; const float* c2  = (const float*)d_in[39];

  const int N = in_sizes[0] / 128;   // 50000
  const int E = in_sizes[1] / 2;     // 250000

  float* ws = (float*)d_ws;
  float* B0 = ws;                        // N*256
  float* B1 = B0 + (size_t)N * 256;      // N*256
  float* B2 = B1 + (size_t)N * 256;      // N*256
  int* rowptr = (int*)(B2 + (size_t)N * 256);  // N+1
  int* cnt    = rowptr + (N + 1);              // N (also used as fill)
  int* csrs   = cnt + N;                       // E
  int* chks   = csrs + E;                      // 64 (nch=49 <= 64)
  float* accbuf = (float*)(chks + 64);         // 2

  size_t need = ((size_t)3 * N * 256) * 4 + ((size_t)2 * N + 1 + E + 64) * 4 + 8;
  if (ws_size < need) return;

  float* out = (float*)d_out;
  dim3 blk(256);
  dim3 gemm1g((N + 63) / 64, 256 / 64);
  dim3 gemm2g((N + 63) / 64, 128 / 64);
  int ng  = (N + 3) / 4;          // node kernels: 4 nodes/block
  int egE = (E + 255) / 256;
  int egN = (N + 255) / 256;
  int nch = (N + 1023) / 1024;    // 49 (must be <= 64 for csr_scan2)

  // ================= CSR build (shared by all convs) =================
  (void)hipMemsetAsync(cnt, 0, (size_t)N * sizeof(int), stream);
  csr_hist<<<egE, blk, 0, stream>>>(ei, E, cnt);
  csr_scan1<<<nch, blk, 0, stream>>>(cnt, rowptr, chks, N);
  csr_scan2<<<1, 64, 0, stream>>>(chks, nch, rowptr, N, E);
  csr_scan3<<<egN, blk, 0, stream>>>(rowptr, chks, N);
  (void)hipMemsetAsync(cnt, 0, (size_t)N * sizeof(int), stream);
  csr_scatter<<<egE, blk, 0, stream>>>(ei, E, rowptr, cnt, csrs);

  // ================= conv1 =================
  sgemm_bias<64,64,32><<<gemm1g, blk, 0, stream>>>(x, Wq1, bq1, B0, N, 128, 256);
  sgemm_bias<64,64,32><<<gemm1g, blk, 0, stream>>>(x, Wk1, bk1, B1, N, 128, 256);
  sgemm_bias<64,64,32><<<gemm1g, blk, 0, stream>>>(x, Wv1, bv1, B2, N, 128, 256);
  attn_fused<256,4><<<ng, blk, 0, stream>>>(rowptr, csrs, B0, B1, B2, B0, N); // o over q
  sgemm_bias<64,64,32><<<gemm1g, blk, 0, stream>>>(x, Ws1, bs1, B1, N, 128, 256); // xr (k1 dead)
  node_gate2<256><<<ng, blk, 0, stream>>>(B0, B1, Wb1, g1, be1, m1, v1, B2, N);   // h -> B2

  // ================= conv2 (input h = B2) =================
  float* q2p = B0;                       // N*128
  float* k2p = B0 + (size_t)N * 128;     // N*128
  float* v2p = B1;                       // N*128
  float* s2p = B1 + (size_t)N * 128;     // N*128
  sgemm_bias<64,64,32><<<gemm2g, blk, 0, stream>>>(B2, Wq2, bq2, q2p, N, 256, 128);
  sgemm_bias<64,64,32><<<gemm2g, blk, 0, stream>>>(B2, Wk2, bk2, k2p, N, 256, 128);
  sgemm_bias<64,64,32><<<gemm2g, blk, 0, stream>>>(B2, Wv2, bv2, v2p, N, 256, 128);
  attn_fused<128,4><<<ng, blk, 0, stream>>>(rowptr, csrs, q2p, k2p, v2p, q2p, N);  // o over q2p
  sgemm_bias<64,64,32><<<gemm2g, blk, 0, stream>>>(B2, Ws2, bs2, s2p, N, 256, 128); // xr
  float* z = k2p;                        // z over k2p (dead after attn2)
  node_gate2<128><<<ng, blk, 0, stream>>>(q2p, s2p, Wb2, g2, be2, m2, v2, z, N);

  // ================= loss =================
  (void)hipMemsetAsync(accbuf, 0, 2 * sizeof(float), stream);
  loss_kernel<<<1024, blk, 0, stream>>>(ei, nei, z, E, accbuf);

  // ================= conv3 (input z), scratch in B1 =================
  float* q3 = B1;
  float* k3 = B1 + (size_t)N;
  float* v3 = B1 + (size_t)2 * N;
  float* s3 = B1 + (size_t)3 * N;
  gemv4<<<ng, blk, 0, stream>>>(z, Wq3, bq3, Wk3, bk3, Wv3, bv3, Ws3, bs3, q3, k3, v3, s3, N);
  attn3_node<<<egN, blk, 0, stream>>>(rowptr, csrs, q3, k3, v3, s3, Wb3, out, N);

  finalize_kernel<<<1, 1, 0, stream>>>(accbuf, c1, c2, out, N, E);
}

// Round 10
// 852.329 us; speedup vs baseline: 2.5278x; 1.0482x over previous
//
#include <hip/hip_runtime.h>
#include <hip/hip_bf16.h>

typedef _Float16 half8 __attribute__((ext_vector_type(8)));
typedef float f32x4 __attribute__((ext_vector_type(4)));

// ---------- weight prep: W[K][D] f32 -> Wt[D][K] fp16, 4 weights per conv ----------
__global__ __launch_bounds__(256) void prep_w(
    const float* __restrict__ W0, const float* __restrict__ W1,
    const float* __restrict__ W2, const float* __restrict__ W3,
    _Float16* __restrict__ T, int K, int D)
{
  int idx = blockIdx.x * 256 + threadIdx.x;
  int tot = K * D;
  if (idx >= 4 * tot) return;
  int which = idx / tot, rem = idx - which * tot;
  int d = rem / K, k = rem - d * K;
  const float* W = which == 0 ? W0 : which == 1 ? W1 : which == 2 ? W2 : W3;
  T[idx] = (_Float16)W[(long long)k * D + d];
}

// ---------- MFMA GEMM: C[Nr,Dout] = A[Nr,K](f32, cvt on the fly) @ Wt^T + bias ----------
// Wt is [Dout][K] fp16 row-major. 64x64 block tile, 4 waves (2x2), each wave 32x32.
template<int K>
__global__ __launch_bounds__(256) void mfma_gemm(
    const float* __restrict__ A, const _Float16* __restrict__ Wt,
    const float* __restrict__ bias, float* __restrict__ C, int Nr, int Dout)
{
  int lane = threadIdx.x & 63;
  int w    = threadIdx.x >> 6;
  int wm = w >> 1, wn = w & 1;
  int row0 = blockIdx.x * 64 + wm * 32;
  int col0 = blockIdx.y * 64 + wn * 32;
  int lr = lane & 15;
  int lk = (lane >> 4) * 8;

  f32x4 acc[2][2] = {};
#pragma unroll
  for (int kb = 0; kb < K; kb += 32) {
    half8 a[2], b[2];
#pragma unroll
    for (int mt = 0; mt < 2; ++mt) {
      int row = row0 + mt * 16 + lr;
      if (row < Nr) {
        const float* p = A + (long long)row * K + kb + lk;
        float4 f0 = *(const float4*)p;
        float4 f1 = *(const float4*)(p + 4);
        a[mt][0] = (_Float16)f0.x; a[mt][1] = (_Float16)f0.y;
        a[mt][2] = (_Float16)f0.z; a[mt][3] = (_Float16)f0.w;
        a[mt][4] = (_Float16)f1.x; a[mt][5] = (_Float16)f1.y;
        a[mt][6] = (_Float16)f1.z; a[mt][7] = (_Float16)f1.w;
      } else {
        a[mt] = half8{};
      }
    }
#pragma unroll
    for (int nt = 0; nt < 2; ++nt) {
      int col = col0 + nt * 16 + lr;
      b[nt] = *(const half8*)(Wt + (long long)col * K + kb + lk);
    }
#pragma unroll
    for (int mt = 0; mt < 2; ++mt)
#pragma unroll
      for (int nt = 0; nt < 2; ++nt)
        acc[mt][nt] = __builtin_amdgcn_mfma_f32_16x16x32_f16(a[mt], b[nt], acc[mt][nt], 0, 0, 0);
  }
  // epilogue: D layout col=lane&15, row=(lane>>4)*4+i  [m89/m91]
#pragma unroll
  for (int nt = 0; nt < 2; ++nt) {
    int col = col0 + nt * 16 + lr;
    float bc = bias[col];
#pragma unroll
    for (int mt = 0; mt < 2; ++mt) {
      int r0 = row0 + mt * 16 + (lane >> 4) * 4;
#pragma unroll
      for (int i = 0; i < 4; ++i) {
        int row = r0 + i;
        if (row < Nr) C[(long long)row * Dout + col] = acc[mt][nt][i] + bc;
      }
    }
  }
}

// ================= CSR build (dst-indexed), reused by all 3 convs =================
__global__ __launch_bounds__(256) void csr_hist(
    const int* __restrict__ ei, int E, int* __restrict__ cnt)
{
  int e = blockIdx.x * 256 + threadIdx.x;
  if (e >= E) return;
  atomicAdd(&cnt[ei[E + e]], 1);
}

__global__ __launch_bounds__(256) void csr_scan1(
    const int* __restrict__ cnt, int* __restrict__ excl,
    int* __restrict__ chunkSums, int N)
{
  int b = blockIdx.x, t = threadIdx.x;
  int lane = t & 63, w = t >> 6;
  int base = b * 1024 + t * 4;
  int c[4];
#pragma unroll
  for (int j = 0; j < 4; ++j) c[j] = (base + j < N) ? cnt[base + j] : 0;
  int ts = c[0] + c[1] + c[2] + c[3];
  int s = ts;
#pragma unroll
  for (int d = 1; d < 64; d <<= 1) {
    int u = __shfl_up(s, d, 64);
    if (lane >= d) s += u;
  }
  __shared__ int wsum[4];
  if (lane == 63) wsum[w] = s;
  __syncthreads();
  int woff = 0;
  for (int i = 0; i < w; ++i) woff += wsum[i];
  int off = woff + s - ts;
#pragma unroll
  for (int j = 0; j < 4; ++j) {
    if (base + j < N) excl[base + j] = off;
    off += c[j];
  }
  if (t == 0) chunkSums[b] = wsum[0] + wsum[1] + wsum[2] + wsum[3];
}

__global__ void csr_scan2(int* __restrict__ chunkSums, int nch,
                          int* __restrict__ rowptr, int N, int E)
{
  int lane = threadIdx.x;
  int v = (lane < nch) ? chunkSums[lane] : 0;
  int s = v;
#pragma unroll
  for (int d = 1; d < 64; d <<= 1) {
    int u = __shfl_up(s, d, 64);
    if (lane >= d) s += u;
  }
  if (lane < nch) chunkSums[lane] = s - v;
  if (lane == 0) rowptr[N] = E;
}

__global__ __launch_bounds__(256) void csr_scan3(
    int* __restrict__ rowptr, const int* __restrict__ chunkSums, int N)
{
  int i = blockIdx.x * 256 + threadIdx.x;
  if (i < N) rowptr[i] += chunkSums[i >> 10];
}

__global__ __launch_bounds__(256) void csr_scatter(
    const int* __restrict__ ei, int E, const int* __restrict__ rowptr,
    int* __restrict__ fill, int* __restrict__ csr_src)
{
  int e = blockIdx.x * 256 + threadIdx.x;
  if (e >= E) return;
  int s = ei[e], d = ei[E + e];
  int pos = atomicAdd(&fill[d], 1);
  csr_src[rowptr[d] + pos] = s;
}

// ================= fused per-node online-softmax attention =================
template<int D, int H>
__global__ __launch_bounds__(256) void attn_fused(
    const int* __restrict__ rowptr, const int* __restrict__ csr_src,
    const float* __restrict__ q, const float* __restrict__ k,
    const float* __restrict__ v, float* __restrict__ o, int N)
{
  constexpr int PER = D / 64;
  constexpr int DH  = D / H;
  int node = blockIdx.x * 4 + (threadIdx.x >> 6);
  if (node >= N) return;
  int lane = threadIdx.x & 63;
  int j0   = lane * PER;
  const float inv = 1.0f / sqrtf((float)DH);

  float qv[PER];
  if constexpr (PER == 4) {
    float4 t4 = *(const float4*)(q + (long long)node * D + j0);
    qv[0]=t4.x; qv[1]=t4.y; qv[2]=t4.z; qv[3]=t4.w;
  } else {
    float2 t2 = *(const float2*)(q + (long long)node * D + j0);
    qv[0]=t2.x; qv[1]=t2.y;
  }

  float m = -INFINITY, den = 0.f;
  float acc[PER] = {};
  int beg = rowptr[node], end = rowptr[node + 1];
  for (int i = beg; i < end; ++i) {
    int s = csr_src[i];
    float kv[PER], vv[PER];
    if constexpr (PER == 4) {
      float4 t4 = *(const float4*)(k + (long long)s * D + j0);
      kv[0]=t4.x; kv[1]=t4.y; kv[2]=t4.z; kv[3]=t4.w;
      float4 u4 = *(const float4*)(v + (long long)s * D + j0);
      vv[0]=u4.x; vv[1]=u4.y; vv[2]=u4.z; vv[3]=u4.w;
    } else {
      float2 t2 = *(const float2*)(k + (long long)s * D + j0);
      kv[0]=t2.x; kv[1]=t2.y;
      float2 u2 = *(const float2*)(v + (long long)s * D + j0);
      vv[0]=u2.x; vv[1]=u2.y;
    }
    float dot = 0.f;
#pragma unroll
    for (int j = 0; j < PER; ++j) dot += qv[j] * kv[j];
    dot += __shfl_xor(dot, 8, 64);
    dot += __shfl_xor(dot, 4, 64);
    dot += __shfl_xor(dot, 2, 64);
    dot += __shfl_xor(dot, 1, 64);
    float score = dot * inv;
    float nm = fmaxf(m, score);
    float scale = __expf(m - nm);
    float p = __expf(score - nm);
    den = den * scale + p;
#pragma unroll
    for (int j = 0; j < PER; ++j) acc[j] = acc[j] * scale + p * vv[j];
    m = nm;
  }
  float r = 1.f / (den + 1e-16f);
  if constexpr (PER == 4) {
    float4 w4; w4.x = acc[0]*r; w4.y = acc[1]*r; w4.z = acc[2]*r; w4.w = acc[3]*r;
    *(float4*)(o + (long long)node * D + j0) = w4;
  } else {
    float2 w2; w2.x = acc[0]*r; w2.y = acc[1]*r;
    *(float2*)(o + (long long)node * D + j0) = w2;
  }
}

// ---------- node: beta-gate, BN(eval), ELU ----------
template<int D>
__global__ __launch_bounds__(256) void node_gate2(
    const float* __restrict__ o, const float* __restrict__ xr,
    const float* __restrict__ Wb, const float* __restrict__ g,
    const float* __restrict__ be, const float* __restrict__ bm,
    const float* __restrict__ bv, float* __restrict__ out, int N)
{
  constexpr int PER = D / 64;
  int node = blockIdx.x * 4 + (threadIdx.x >> 6);
  if (node >= N) return;
  int lane = threadIdx.x & 63;
  int j0   = lane * PER;
  float ov[PER], xv[PER];
  if constexpr (PER == 4) {
    float4 o4 = *(const float4*)(o  + (long long)node * D + j0);
    float4 x4 = *(const float4*)(xr + (long long)node * D + j0);
    ov[0]=o4.x; ov[1]=o4.y; ov[2]=o4.z; ov[3]=o4.w;
    xv[0]=x4.x; xv[1]=x4.y; xv[2]=x4.z; xv[3]=x4.w;
  } else {
    float2 o2 = *(const float2*)(o  + (long long)node * D + j0);
    float2 x2 = *(const float2*)(xr + (long long)node * D + j0);
    ov[0]=o2.x; ov[1]=o2.y;
    xv[0]=x2.x; xv[1]=x2.y;
  }
  float dot = 0.f;
#pragma unroll
  for (int i = 0; i < PER; ++i) {
    int j = j0 + i;
    dot += ov[i] * Wb[j] + xv[i] * Wb[D + j] + (ov[i] - xv[i]) * Wb[2 * D + j];
  }
#pragma unroll
  for (int off = 32; off >= 1; off >>= 1) dot += __shfl_xor(dot, off, 64);
  float beta = 1.f / (1.f + expf(-dot));
  float res[PER];
#pragma unroll
  for (int i = 0; i < PER; ++i) {
    int j = j0 + i;
    float h = beta * xv[i] + (1.f - beta) * ov[i];
    float y = (h - bm[j]) * rsqrtf(bv[j] + 1e-5f) * g[j] + be[j];
    res[i] = y > 0.f ? y : expf(y) - 1.f;
  }
  if constexpr (PER == 4) {
    float4 w; w.x=res[0]; w.y=res[1]; w.z=res[2]; w.w=res[3];
    *(float4*)(out + (long long)node * D + j0) = w;
  } else {
    float2 w; w.x=res[0]; w.y=res[1];
    *(float2*)(out + (long long)node * D + j0) = w;
  }
}

// ---------- loss ----------
__global__ __launch_bounds__(256) void loss_kernel(
    const int* __restrict__ ei, const int* __restrict__ nei,
    const float* __restrict__ z, int E, float* __restrict__ acc)
{
  int lane = threadIdx.x & 63;
  int wib  = threadIdx.x >> 6;
  int sub  = lane >> 5, r = lane & 31;
  long long gw = ((long long)blockIdx.x * blockDim.x + threadIdx.x) >> 6;
  long long nw = ((long long)gridDim.x * blockDim.x) >> 6;
  float lpos = 0.f, lneg = 0.f;
  for (long long w = gw * 2 + sub; w < 2LL * E; w += nw * 2) {
    int isneg = (w >= E);
    const int* ep = isneg ? nei : ei;
    long long idx = isneg ? w - E : w;
    int s = ep[idx], d = ep[E + idx];
    float4 a = *(const float4*)(z + (long long)s * 128 + r * 4);
    float4 b = *(const float4*)(z + (long long)d * 128 + r * 4);
    float dot = a.x * b.x + a.y * b.y + a.z * b.z + a.w * b.w;
#pragma unroll
    for (int off = 16; off >= 1; off >>= 1) dot += __shfl_xor(dot, off, 64);
    if (r == 0) {
      float sg = 1.f / (1.f + expf(-dot));
      if (isneg) lneg += -logf(1.f - sg + 1e-15f);
      else       lpos += -logf(sg + 1e-15f);
    }
  }
#pragma unroll
  for (int off = 32; off >= 1; off >>= 1) {
    lpos += __shfl_xor(lpos, off, 64);
    lneg += __shfl_xor(lneg, off, 64);
  }
  __shared__ float sp[4], sn[4];
  if (lane == 0) { sp[wib] = lpos; sn[wib] = lneg; }
  __syncthreads();
  if (threadIdx.x == 0) {
    float P = 0.f, Ng = 0.f;
    for (int i = 0; i < 4; ++i) { P += sp[i]; Ng += sn[i]; }
    atomicAdd(acc, P);
    atomicAdd(acc + 1, Ng);
  }
}

// ---------- conv3: fused 4-way GEMV ----------
__global__ __launch_bounds__(256) void gemv4(
    const float* __restrict__ z,
    const float* __restrict__ Wq, const float* __restrict__ bq,
    const float* __restrict__ Wk, const float* __restrict__ bk,
    const float* __restrict__ Wv, const float* __restrict__ bv,
    const float* __restrict__ Ws, const float* __restrict__ bs,
    float* __restrict__ q3, float* __restrict__ k3,
    float* __restrict__ v3, float* __restrict__ s3, int N)
{
  int node = blockIdx.x * 4 + (threadIdx.x >> 6);
  if (node >= N) return;
  int lane = threadIdx.x & 63;
  float2 zv = *(const float2*)(z + (long long)node * 128 + lane * 2);
  float aq = zv.x * Wq[lane*2] + zv.y * Wq[lane*2+1];
  float ak = zv.x * Wk[lane*2] + zv.y * Wk[lane*2+1];
  float av = zv.x * Wv[lane*2] + zv.y * Wv[lane*2+1];
  float as_ = zv.x * Ws[lane*2] + zv.y * Ws[lane*2+1];
#pragma unroll
  for (int off = 32; off >= 1; off >>= 1) {
    aq  += __shfl_xor(aq,  off, 64);
    ak  += __shfl_xor(ak,  off, 64);
    av  += __shfl_xor(av,  off, 64);
    as_ += __shfl_xor(as_, off, 64);
  }
  if (lane == 0) {
    q3[node] = aq + bq[0];
    k3[node] = ak + bk[0];
    v3[node] = av + bv[0];
    s3[node] = as_ + bs[0];
  }
}

__global__ __launch_bounds__(256) void attn3_node(
    const int* __restrict__ rowptr, const int* __restrict__ csr_src,
    const float* __restrict__ q3, const float* __restrict__ k3,
    const float* __restrict__ v3, const float* __restrict__ s3,
    const float* __restrict__ Wb3, float* __restrict__ out, int N)
{
  int n = blockIdx.x * 256 + threadIdx.x;
  if (n >= N) return;
  float qd = q3[n];
  float m = -INFINITY, den = 0.f, acc = 0.f;
  int beg = rowptr[n], end = rowptr[n + 1];
  for (int i = beg; i < end; ++i) {
    int s = csr_src[i];
    float sc = qd * k3[s];
    float nm = fmaxf(m, sc);
    float scale = __expf(m - nm);
    float p = __expf(sc - nm);
    den = den * scale + p;
    acc = acc * scale + p * v3[s];
    m = nm;
  }
  float on = acc / (den + 1e-16f);
  float xr = s3[n];
  float tv = on * Wb3[0] + xr * Wb3[1] + (on - xr) * Wb3[2];
  float b = 1.f / (1.f + expf(-tv));
  out[n] = b * xr + (1.f - b) * on;
}

__global__ void finalize_kernel(const float* __restrict__ acc,
                                const float* __restrict__ c1, const float* __restrict__ c2,
                                float* __restrict__ out, int N, int E)
{
  out[N]     = acc[0] / (float)E + acc[1] / (float)E;
  out[N + 1] = c1[0];
  out[N + 2] = c2[0];
}

// ---------- orchestration ----------
extern "C" void kernel_launch(void* const* d_in, const int* in_sizes, int n_in,
                              void* d_out, int out_size, void* d_ws, size_t ws_size,
                              hipStream_t stream)
{
  const float* x   = (const float*)d_in[0];
  const int*   ei  = (const int*)d_in[1];
  const int*   nei = (const int*)d_in[2];
  const float* Wq1 = (const float*)d_in[3];  const float* bq1 = (const float*)d_in[4];
  const float* Wk1 = (const float*)d_in[5];  const float* bk1 = (const float*)d_in[6];
  const float* Wv1 = (const float*)d_in[7];  const float* bv1 = (const float*)d_in[8];
  const float* Ws1 = (const float*)d_in[9];  const float* bs1 = (const float*)d_in[10];
  const float* Wb1 = (const float*)d_in[11];
  const float* g1  = (const float*)d_in[12]; const float* be1 = (const float*)d_in[13];
  const float* m1  = (const float*)d_in[14]; const float* v1  = (const float*)d_in[15];
  const float* Wq2 = (const float*)d_in[16]; const float* bq2 = (const float*)d_in[17];
  const float* Wk2 = (const float*)d_in[18]; const float* bk2 = (const float*)d_in[19];
  const float* Wv2 = (const float*)d_in[20]; const float* bv2 = (const float*)d_in[21];
  const float* Ws2 = (const float*)d_in[22]; const float* bs2 = (const float*)d_in[23];
  const float* Wb2 = (const float*)d_in[24];
  const float* g2  = (const float*)d_in[25]; const float* be2 = (const float*)d_in[26];
  const float* m2  = (const float*)d_in[27]; const float* v2  = (const float*)d_in[28];
  const float* Wq3 = (const float*)d_in[29]; const float* bq3 = (const float*)d_in[30];
  const float* Wk3 = (const float*)d_in[31]; const float* bk3 = (const float*)d_in[32];
  const float* Wv3 = (const float*)d_in[33]; const float* bv3 = (const float*)d_in[34];
  const float* Ws3 = (const float*)d_in[35]; const float* bs3 = (const float*)d_in[36];
  const float* Wb3 = (const float*)d_in[37];
  const float* c1  = (const float*)d_in[38]; const float* c2  = (const float*)d_in[39];

  const int N = in_sizes[0] / 128;   // 50000
  const int E = in_sizes[1] / 2;     // 250000

  float* ws = (float*)d_ws;
  float* B0 = ws;                        // N*256
  float* B1 = B0 + (size_t)N * 256;      // N*256
  float* B2 = B1 + (size_t)N * 256;      // N*256
  int* rowptr = (int*)(B2 + (size_t)N * 256);  // N+1
  int* cnt    = rowptr + (N + 1);              // N (also used as fill)
  int* csrs   = cnt + N;                       // E
  int* chks   = csrs + E;                      // 64
  float* accbuf = (float*)(chks + 64);         // 2
  uintptr_t wp = ((uintptr_t)(accbuf + 2) + 63) & ~(uintptr_t)63;
  _Float16* wt1 = (_Float16*)wp;               // 4 * 128*256 halves
  _Float16* wt2 = wt1 + 4 * 32768;             // 4 * 256*128 halves

  size_t need = ((size_t)3 * N * 256) * 4 + ((size_t)2 * N + 1 + E + 64) * 4 + 8
              + 64 + 8 * 32768 * sizeof(_Float16);
  if (ws_size < need) return;

  float* out = (float*)d_out;
  dim3 blk(256);
  int ng  = (N + 3) / 4;
  int egE = (E + 255) / 256;
  int egN = (N + 255) / 256;
  int nch = (N + 1023) / 1024;    // 49 (<= 64)
  dim3 g1grid((N + 63) / 64, 256 / 64);   // conv1 GEMMs: Dout=256
  dim3 g2grid((N + 63) / 64, 128 / 64);   // conv2 GEMMs: Dout=128

  // ================= weight prep (fp16, transposed) =================
  prep_w<<<(4 * 32768 + 255) / 256, blk, 0, stream>>>(Wq1, Wk1, Wv1, Ws1, wt1, 128, 256);
  prep_w<<<(4 * 32768 + 255) / 256, blk, 0, stream>>>(Wq2, Wk2, Wv2, Ws2, wt2, 256, 128);

  // ================= CSR build =================
  (void)hipMemsetAsync(cnt, 0, (size_t)N * sizeof(int), stream);
  csr_hist<<<egE, blk, 0, stream>>>(ei, E, cnt);
  csr_scan1<<<nch, blk, 0, stream>>>(cnt, rowptr, chks, N);
  csr_scan2<<<1, 64, 0, stream>>>(chks, nch, rowptr, N, E);
  csr_scan3<<<egN, blk, 0, stream>>>(rowptr, chks, N);
  (void)hipMemsetAsync(cnt, 0, (size_t)N * sizeof(int), stream);
  csr_scatter<<<egE, blk, 0, stream>>>(ei, E, rowptr, cnt, csrs);

  // ================= conv1 (K=128, Dout=256) =================
  mfma_gemm<128><<<g1grid, blk, 0, stream>>>(x, wt1 + 0 * 32768, bq1, B0, N, 256);
  mfma_gemm<128><<<g1grid, blk, 0, stream>>>(x, wt1 + 1 * 32768, bk1, B1, N, 256);
  mfma_gemm<128><<<g1grid, blk, 0, stream>>>(x, wt1 + 2 * 32768, bv1, B2, N, 256);
  attn_fused<256,4><<<ng, blk, 0, stream>>>(rowptr, csrs, B0, B1, B2, B0, N); // o over q
  mfma_gemm<128><<<g1grid, blk, 0, stream>>>(x, wt1 + 3 * 32768, bs1, B1, N, 256); // xr
  node_gate2<256><<<ng, blk, 0, stream>>>(B0, B1, Wb1, g1, be1, m1, v1, B2, N);    // h -> B2

  // ================= conv2 (K=256, Dout=128) =================
  float* q2p = B0;
  float* k2p = B0 + (size_t)N * 128;
  float* v2p = B1;
  float* s2p = B1 + (size_t)N * 128;
  mfma_gemm<256><<<g2grid, blk, 0, stream>>>(B2, wt2 + 0 * 32768, bq2, q2p, N, 128);
  mfma_gemm<256><<<g2grid, blk, 0, stream>>>(B2, wt2 + 1 * 32768, bk2, k2p, N, 128);
  mfma_gemm<256><<<g2grid, blk, 0, stream>>>(B2, wt2 + 2 * 32768, bv2, v2p, N, 128);
  attn_fused<128,4><<<ng, blk, 0, stream>>>(rowptr, csrs, q2p, k2p, v2p, q2p, N);
  mfma_gemm<256><<<g2grid, blk, 0, stream>>>(B2, wt2 + 3 * 32768, bs2, s2p, N, 128);
  float* z = k2p;
  node_gate2<128><<<ng, blk, 0, stream>>>(q2p, s2p, Wb2, g2, be2, m2, v2, z, N);

  // ================= loss =================
  (void)hipMemsetAsync(accbuf, 0, 2 * sizeof(float), stream);
  loss_kernel<<<1024, blk, 0, stream>>>(ei, nei, z, E, accbuf);

  // ================= conv3 =================
  float* q3 = B1;
  float* k3 = B1 + (size_t)N;
  float* v3 = B1 + (size_t)2 * N;
  float* s3 = B1 + (size_t)3 * N;
  gemv4<<<ng, blk, 0, stream>>>(z, Wq3, bq3, Wk3, bk3, Wv3, bv3, Ws3, bs3, q3, k3, v3, s3, N);
  attn3_node<<<egN, blk, 0, stream>>>(rowptr, csrs, q3, k3, v3, s3, Wb3, out, N);

  finalize_kernel<<<1, 1, 0, stream>>>(accbuf, c1, c2, out, N, E);
}

// Round 11
// 798.835 us; speedup vs baseline: 2.6971x; 1.0670x over previous
//
#include <hip/hip_runtime.h>
#include <hip/hip_bf16.h>

typedef _Float16 half8 __attribute__((ext_vector_type(8)));
typedef _Float16 half4 __attribute__((ext_vector_type(4)));
typedef _Float16 half2v __attribute__((ext_vector_type(2)));
typedef float f32x4 __attribute__((ext_vector_type(4)));

// ---------- weight prep: W[K][D] f32 -> Wt[D][K] fp16, 4 weights per conv ----------
__global__ __launch_bounds__(256) void prep_w(
    const float* __restrict__ W0, const float* __restrict__ W1,
    const float* __restrict__ W2, const float* __restrict__ W3,
    _Float16* __restrict__ T, int K, int D)
{
  int idx = blockIdx.x * 256 + threadIdx.x;
  int tot = K * D;
  if (idx >= 4 * tot) return;
  int which = idx / tot, rem = idx - which * tot;
  int d = rem / K, k = rem - d * K;
  const float* W = which == 0 ? W0 : which == 1 ? W1 : which == 2 ? W2 : W3;
  T[idx] = (_Float16)W[(long long)k * D + d];
}

// ---------- MFMA GEMM: C[Nr,Dout] = A[Nr,K](f32, cvt on the fly) @ Wt^T + bias ----------
// Wt is [Dout][K] fp16 row-major. 64x64 block tile, 4 waves (2x2), each wave 32x32.
// OutT = float or _Float16 (fp16 outputs feed the gather-bound attention).
template<int K, typename OutT>
__global__ __launch_bounds__(256) void mfma_gemm(
    const float* __restrict__ A, const _Float16* __restrict__ Wt,
    const float* __restrict__ bias, OutT* __restrict__ C, int Nr, int Dout)
{
  int lane = threadIdx.x & 63;
  int w    = threadIdx.x >> 6;
  int wm = w >> 1, wn = w & 1;
  int row0 = blockIdx.x * 64 + wm * 32;
  int col0 = blockIdx.y * 64 + wn * 32;
  int lr = lane & 15;
  int lk = (lane >> 4) * 8;

  f32x4 acc[2][2] = {};
#pragma unroll
  for (int kb = 0; kb < K; kb += 32) {
    half8 a[2], b[2];
#pragma unroll
    for (int mt = 0; mt < 2; ++mt) {
      int row = row0 + mt * 16 + lr;
      if (row < Nr) {
        const float* p = A + (long long)row * K + kb + lk;
        float4 f0 = *(const float4*)p;
        float4 f1 = *(const float4*)(p + 4);
        a[mt][0] = (_Float16)f0.x; a[mt][1] = (_Float16)f0.y;
        a[mt][2] = (_Float16)f0.z; a[mt][3] = (_Float16)f0.w;
        a[mt][4] = (_Float16)f1.x; a[mt][5] = (_Float16)f1.y;
        a[mt][6] = (_Float16)f1.z; a[mt][7] = (_Float16)f1.w;
      } else {
        a[mt] = half8{};
      }
    }
#pragma unroll
    for (int nt = 0; nt < 2; ++nt) {
      int col = col0 + nt * 16 + lr;
      b[nt] = *(const half8*)(Wt + (long long)col * K + kb + lk);
    }
#pragma unroll
    for (int mt = 0; mt < 2; ++mt)
#pragma unroll
      for (int nt = 0; nt < 2; ++nt)
        acc[mt][nt] = __builtin_amdgcn_mfma_f32_16x16x32_f16(a[mt], b[nt], acc[mt][nt], 0, 0, 0);
  }
  // epilogue: D layout col=lane&15, row=(lane>>4)*4+i  [m89/m91]
#pragma unroll
  for (int nt = 0; nt < 2; ++nt) {
    int col = col0 + nt * 16 + lr;
    float bc = bias[col];
#pragma unroll
    for (int mt = 0; mt < 2; ++mt) {
      int r0 = row0 + mt * 16 + (lane >> 4) * 4;
#pragma unroll
      for (int i = 0; i < 4; ++i) {
        int row = r0 + i;
        if (row < Nr) C[(long long)row * Dout + col] = (OutT)(acc[mt][nt][i] + bc);
      }
    }
  }
}

// ================= CSR build (dst-indexed), reused by all 3 convs =================
__global__ __launch_bounds__(256) void csr_hist(
    const int* __restrict__ ei, int E, int* __restrict__ cnt)
{
  int e = blockIdx.x * 256 + threadIdx.x;
  if (e >= E) return;
  atomicAdd(&cnt[ei[E + e]], 1);
}

__global__ __launch_bounds__(256) void csr_scan1(
    const int* __restrict__ cnt, int* __restrict__ excl,
    int* __restrict__ chunkSums, int N)
{
  int b = blockIdx.x, t = threadIdx.x;
  int lane = t & 63, w = t >> 6;
  int base = b * 1024 + t * 4;
  int c[4];
#pragma unroll
  for (int j = 0; j < 4; ++j) c[j] = (base + j < N) ? cnt[base + j] : 0;
  int ts = c[0] + c[1] + c[2] + c[3];
  int s = ts;
#pragma unroll
  for (int d = 1; d < 64; d <<= 1) {
    int u = __shfl_up(s, d, 64);
    if (lane >= d) s += u;
  }
  __shared__ int wsum[4];
  if (lane == 63) wsum[w] = s;
  __syncthreads();
  int woff = 0;
  for (int i = 0; i < w; ++i) woff += wsum[i];
  int off = woff + s - ts;
#pragma unroll
  for (int j = 0; j < 4; ++j) {
    if (base + j < N) excl[base + j] = off;
    off += c[j];
  }
  if (t == 0) chunkSums[b] = wsum[0] + wsum[1] + wsum[2] + wsum[3];
}

__global__ void csr_scan2(int* __restrict__ chunkSums, int nch,
                          int* __restrict__ rowptr, int N, int E)
{
  int lane = threadIdx.x;
  int v = (lane < nch) ? chunkSums[lane] : 0;
  int s = v;
#pragma unroll
  for (int d = 1; d < 64; d <<= 1) {
    int u = __shfl_up(s, d, 64);
    if (lane >= d) s += u;
  }
  if (lane < nch) chunkSums[lane] = s - v;
  if (lane == 0) rowptr[N] = E;
}

__global__ __launch_bounds__(256) void csr_scan3(
    int* __restrict__ rowptr, const int* __restrict__ chunkSums, int N)
{
  int i = blockIdx.x * 256 + threadIdx.x;
  if (i < N) rowptr[i] += chunkSums[i >> 10];
}

__global__ __launch_bounds__(256) void csr_scatter(
    const int* __restrict__ ei, int E, const int* __restrict__ rowptr,
    int* __restrict__ fill, int* __restrict__ csr_src)
{
  int e = blockIdx.x * 256 + threadIdx.x;
  if (e >= E) return;
  int s = ei[e], d = ei[E + e];
  int pos = atomicAdd(&fill[d], 1);
  csr_src[rowptr[d] + pos] = s;
}

// ================= fused per-node online-softmax attention (fp16 k/v gathers) =================
template<int D, int H>
__global__ __launch_bounds__(256) void attn_fused(
    const int* __restrict__ rowptr, const int* __restrict__ csr_src,
    const float* __restrict__ q, const _Float16* __restrict__ k,
    const _Float16* __restrict__ v, float* __restrict__ o, int N)
{
  constexpr int PER = D / 64;
  constexpr int DH  = D / H;
  int node = blockIdx.x * 4 + (threadIdx.x >> 6);
  if (node >= N) return;
  int lane = threadIdx.x & 63;
  int j0   = lane * PER;
  const float inv = 1.0f / sqrtf((float)DH);

  float qv[PER];
  if constexpr (PER == 4) {
    float4 t4 = *(const float4*)(q + (long long)node * D + j0);
    qv[0]=t4.x; qv[1]=t4.y; qv[2]=t4.z; qv[3]=t4.w;
  } else {
    float2 t2 = *(const float2*)(q + (long long)node * D + j0);
    qv[0]=t2.x; qv[1]=t2.y;
  }

  float m = -INFINITY, den = 0.f;
  float acc[PER] = {};
  int beg = rowptr[node], end = rowptr[node + 1];
  for (int i = beg; i < end; ++i) {
    int s = csr_src[i];
    float kv[PER], vv[PER];
    if constexpr (PER == 4) {
      half4 t4 = *(const half4*)(k + (long long)s * D + j0);
      half4 u4 = *(const half4*)(v + (long long)s * D + j0);
#pragma unroll
      for (int j = 0; j < 4; ++j) { kv[j] = (float)t4[j]; vv[j] = (float)u4[j]; }
    } else {
      half2v t2 = *(const half2v*)(k + (long long)s * D + j0);
      half2v u2 = *(const half2v*)(v + (long long)s * D + j0);
#pragma unroll
      for (int j = 0; j < 2; ++j) { kv[j] = (float)t2[j]; vv[j] = (float)u2[j]; }
    }
    float dot = 0.f;
#pragma unroll
    for (int j = 0; j < PER; ++j) dot += qv[j] * kv[j];
    dot += __shfl_xor(dot, 8, 64);
    dot += __shfl_xor(dot, 4, 64);
    dot += __shfl_xor(dot, 2, 64);
    dot += __shfl_xor(dot, 1, 64);
    float score = dot * inv;
    float nm = fmaxf(m, score);
    float scale = __expf(m - nm);
    float p = __expf(score - nm);
    den = den * scale + p;
#pragma unroll
    for (int j = 0; j < PER; ++j) acc[j] = acc[j] * scale + p * vv[j];
    m = nm;
  }
  float r = 1.f / (den + 1e-16f);
  if constexpr (PER == 4) {
    float4 w4; w4.x = acc[0]*r; w4.y = acc[1]*r; w4.z = acc[2]*r; w4.w = acc[3]*r;
    *(float4*)(o + (long long)node * D + j0) = w4;
  } else {
    float2 w2; w2.x = acc[0]*r; w2.y = acc[1]*r;
    *(float2*)(o + (long long)node * D + j0) = w2;
  }
}

// ---------- node: beta-gate, BN(eval), ELU; optional fp16 shadow output ----------
template<int D, bool WRITE_H>
__global__ __launch_bounds__(256) void node_gate2(
    const float* __restrict__ o, const float* __restrict__ xr,
    const float* __restrict__ Wb, const float* __restrict__ g,
    const float* __restrict__ be, const float* __restrict__ bm,
    const float* __restrict__ bv, float* __restrict__ out,
    _Float16* __restrict__ outh, int N)
{
  constexpr int PER = D / 64;
  int node = blockIdx.x * 4 + (threadIdx.x >> 6);
  if (node >= N) return;
  int lane = threadIdx.x & 63;
  int j0   = lane * PER;
  float ov[PER], xv[PER];
  if constexpr (PER == 4) {
    float4 o4 = *(const float4*)(o  + (long long)node * D + j0);
    float4 x4 = *(const float4*)(xr + (long long)node * D + j0);
    ov[0]=o4.x; ov[1]=o4.y; ov[2]=o4.z; ov[3]=o4.w;
    xv[0]=x4.x; xv[1]=x4.y; xv[2]=x4.z; xv[3]=x4.w;
  } else {
    float2 o2 = *(const float2*)(o  + (long long)node * D + j0);
    float2 x2 = *(const float2*)(xr + (long long)node * D + j0);
    ov[0]=o2.x; ov[1]=o2.y;
    xv[0]=x2.x; xv[1]=x2.y;
  }
  float dot = 0.f;
#pragma unroll
  for (int i = 0; i < PER; ++i) {
    int j = j0 + i;
    dot += ov[i] * Wb[j] + xv[i] * Wb[D + j] + (ov[i] - xv[i]) * Wb[2 * D + j];
  }
#pragma unroll
  for (int off = 32; off >= 1; off >>= 1) dot += __shfl_xor(dot, off, 64);
  float beta = 1.f / (1.f + expf(-dot));
  float res[PER];
#pragma unroll
  for (int i = 0; i < PER; ++i) {
    int j = j0 + i;
    float h = beta * xv[i] + (1.f - beta) * ov[i];
    float y = (h - bm[j]) * rsqrtf(bv[j] + 1e-5f) * g[j] + be[j];
    res[i] = y > 0.f ? y : expf(y) - 1.f;
  }
  if constexpr (PER == 4) {
    float4 w; w.x=res[0]; w.y=res[1]; w.z=res[2]; w.w=res[3];
    *(float4*)(out + (long long)node * D + j0) = w;
  } else {
    float2 w; w.x=res[0]; w.y=res[1];
    *(float2*)(out + (long long)node * D + j0) = w;
  }
  if constexpr (WRITE_H) {
    if constexpr (PER == 4) {
      half4 hw; hw[0]=(_Float16)res[0]; hw[1]=(_Float16)res[1];
      hw[2]=(_Float16)res[2]; hw[3]=(_Float16)res[3];
      *(half4*)(outh + (long long)node * D + j0) = hw;
    } else {
      half2v hw; hw[0]=(_Float16)res[0]; hw[1]=(_Float16)res[1];
      *(half2v*)(outh + (long long)node * D + j0) = hw;
    }
  }
}

// ---------- loss: gathers fp16 z rows ----------
__global__ __launch_bounds__(256) void loss_kernel(
    const int* __restrict__ ei, const int* __restrict__ nei,
    const _Float16* __restrict__ zh, int E, float* __restrict__ acc)
{
  int lane = threadIdx.x & 63;
  int wib  = threadIdx.x >> 6;
  int sub  = lane >> 5, r = lane & 31;
  long long gw = ((long long)blockIdx.x * blockDim.x + threadIdx.x) >> 6;
  long long nw = ((long long)gridDim.x * blockDim.x) >> 6;
  float lpos = 0.f, lneg = 0.f;
  for (long long w = gw * 2 + sub; w < 2LL * E; w += nw * 2) {
    int isneg = (w >= E);
    const int* ep = isneg ? nei : ei;
    long long idx = isneg ? w - E : w;
    int s = ep[idx], d = ep[E + idx];
    half4 a = *(const half4*)(zh + (long long)s * 128 + r * 4);
    half4 b = *(const half4*)(zh + (long long)d * 128 + r * 4);
    float dot = (float)a[0]*(float)b[0] + (float)a[1]*(float)b[1]
              + (float)a[2]*(float)b[2] + (float)a[3]*(float)b[3];
#pragma unroll
    for (int off = 16; off >= 1; off >>= 1) dot += __shfl_xor(dot, off, 64);
    if (r == 0) {
      float sg = 1.f / (1.f + expf(-dot));
      if (isneg) lneg += -logf(1.f - sg + 1e-15f);
      else       lpos += -logf(sg + 1e-15f);
    }
  }
#pragma unroll
  for (int off = 32; off >= 1; off >>= 1) {
    lpos += __shfl_xor(lpos, off, 64);
    lneg += __shfl_xor(lneg, off, 64);
  }
  __shared__ float sp[4], sn[4];
  if (lane == 0) { sp[wib] = lpos; sn[wib] = lneg; }
  __syncthreads();
  if (threadIdx.x == 0) {
    float P = 0.f, Ng = 0.f;
    for (int i = 0; i < 4; ++i) { P += sp[i]; Ng += sn[i]; }
    atomicAdd(acc, P);
    atomicAdd(acc + 1, Ng);
  }
}

// ---------- conv3: fused 4-way GEMV ----------
__global__ __launch_bounds__(256) void gemv4(
    const float* __restrict__ z,
    const float* __restrict__ Wq, const float* __restrict__ bq,
    const float* __restrict__ Wk, const float* __restrict__ bk,
    const float* __restrict__ Wv, const float* __restrict__ bv,
    const float* __restrict__ Ws, const float* __restrict__ bs,
    float* __restrict__ q3, float* __restrict__ k3,
    float* __restrict__ v3, float* __restrict__ s3, int N)
{
  int node = blockIdx.x * 4 + (threadIdx.x >> 6);
  if (node >= N) return;
  int lane = threadIdx.x & 63;
  float2 zv = *(const float2*)(z + (long long)node * 128 + lane * 2);
  float aq = zv.x * Wq[lane*2] + zv.y * Wq[lane*2+1];
  float ak = zv.x * Wk[lane*2] + zv.y * Wk[lane*2+1];
  float av = zv.x * Wv[lane*2] + zv.y * Wv[lane*2+1];
  float as_ = zv.x * Ws[lane*2] + zv.y * Ws[lane*2+1];
#pragma unroll
  for (int off = 32; off >= 1; off >>= 1) {
    aq  += __shfl_xor(aq,  off, 64);
    ak  += __shfl_xor(ak,  off, 64);
    av  += __shfl_xor(av,  off, 64);
    as_ += __shfl_xor(as_, off, 64);
  }
  if (lane == 0) {
    q3[node] = aq + bq[0];
    k3[node] = ak + bk[0];
    v3[node] = av + bv[0];
    s3[node] = as_ + bs[0];
  }
}

__global__ __launch_bounds__(256) void attn3_node(
    const int* __restrict__ rowptr, const int* __restrict__ csr_src,
    const float* __restrict__ q3, const float* __restrict__ k3,
    const float* __restrict__ v3, const float* __restrict__ s3,
    const float* __restrict__ Wb3, float* __restrict__ out, int N)
{
  int n = blockIdx.x * 256 + threadIdx.x;
  if (n >= N) return;
  float qd = q3[n];
  float m = -INFINITY, den = 0.f, acc = 0.f;
  int beg = rowptr[n], end = rowptr[n + 1];
  for (int i = beg; i < end; ++i) {
    int s = csr_src[i];
    float sc = qd * k3[s];
    float nm = fmaxf(m, sc);
    float scale = __expf(m - nm);
    float p = __expf(sc - nm);
    den = den * scale + p;
    acc = acc * scale + p * v3[s];
    m = nm;
  }
  float on = acc / (den + 1e-16f);
  float xr = s3[n];
  float tv = on * Wb3[0] + xr * Wb3[1] + (on - xr) * Wb3[2];
  float b = 1.f / (1.f + expf(-tv));
  out[n] = b * xr + (1.f - b) * on;
}

__global__ void finalize_kernel(const float* __restrict__ acc,
                                const float* __restrict__ c1, const float* __restrict__ c2,
                                float* __restrict__ out, int N, int E)
{
  out[N]     = acc[0] / (float)E + acc[1] / (float)E;
  out[N + 1] = c1[0];
  out[N + 2] = c2[0];
}

// ---------- orchestration ----------
extern "C" void kernel_launch(void* const* d_in, const int* in_sizes, int n_in,
                              void* d_out, int out_size, void* d_ws, size_t ws_size,
                              hipStream_t stream)
{
  const float* x   = (const float*)d_in[0];
  const int*   ei  = (const int*)d_in[1];
  const int*   nei = (const int*)d_in[2];
  const float* Wq1 = (const float*)d_in[3];  const float* bq1 = (const float*)d_in[4];
  const float* Wk1 = (const float*)d_in[5];  const float* bk1 = (const float*)d_in[6];
  const float* Wv1 = (const float*)d_in[7];  const float* bv1 = (const float*)d_in[8];
  const float* Ws1 = (const float*)d_in[9];  const float* bs1 = (const float*)d_in[10];
  const float* Wb1 = (const float*)d_in[11];
  const float* g1  = (const float*)d_in[12]; const float* be1 = (const float*)d_in[13];
  const float* m1  = (const float*)d_in[14]; const float* v1  = (const float*)d_in[15];
  const float* Wq2 = (const float*)d_in[16]; const float* bq2 = (const float*)d_in[17];
  const float* Wk2 = (const float*)d_in[18]; const float* bk2 = (const float*)d_in[19];
  const float* Wv2 = (const float*)d_in[20]; const float* bv2 = (const float*)d_in[21];
  const float* Ws2 = (const float*)d_in[22]; const float* bs2 = (const float*)d_in[23];
  const float* Wb2 = (const float*)d_in[24];
  const float* g2  = (const float*)d_in[25]; const float* be2 = (const float*)d_in[26];
  const float* m2  = (const float*)d_in[27]; const float* v2  = (const float*)d_in[28];
  const float* Wq3 = (const float*)d_in[29]; const float* bq3 = (const float*)d_in[30];
  const float* Wk3 = (const float*)d_in[31]; const float* bk3 = (const float*)d_in[32];
  const float* Wv3 = (const float*)d_in[33]; const float* bv3 = (const float*)d_in[34];
  const float* Ws3 = (const float*)d_in[35]; const float* bs3 = (const float*)d_in[36];
  const float* Wb3 = (const float*)d_in[37];
  const float* c1  = (const float*)d_in[38]; const float* c2  = (const float*)d_in[39];

  const int N = in_sizes[0] / 128;   // 50000
  const int E = in_sizes[1] / 2;     // 250000

  float* ws = (float*)d_ws;
  float* B0 = ws;                        // N*256 f32
  float* B1 = B0 + (size_t)N * 256;      // N*256 f32
  float* B2 = B1 + (size_t)N * 256;      // N*256 f32
  int* rowptr = (int*)(B2 + (size_t)N * 256);  // N+1
  int* cnt    = rowptr + (N + 1);              // N (also fill)
  int* csrs   = cnt + N;                       // E
  int* chks   = csrs + E;                      // 64
  float* accbuf = (float*)(chks + 64);         // 2
  uintptr_t wp = ((uintptr_t)(accbuf + 2) + 63) & ~(uintptr_t)63;
  _Float16* wt1 = (_Float16*)wp;               // 4 * 128*256
  _Float16* wt2 = wt1 + 4 * 32768;             // 4 * 256*128

  size_t need = ((size_t)3 * N * 256) * 4 + ((size_t)2 * N + 1 + E + 64) * 4 + 8
              + 64 + 8 * 32768 * sizeof(_Float16);
  if (ws_size < need) return;

  float* out = (float*)d_out;
  dim3 blk(256);
  int ng  = (N + 3) / 4;
  int egE = (E + 255) / 256;
  int egN = (N + 255) / 256;
  int nch = (N + 1023) / 1024;    // 49 (<= 64)
  dim3 g1grid((N + 63) / 64, 256 / 64);
  dim3 g2grid((N + 63) / 64, 128 / 64);

  // ================= weight prep =================
  prep_w<<<(4 * 32768 + 255) / 256, blk, 0, stream>>>(Wq1, Wk1, Wv1, Ws1, wt1, 128, 256);
  prep_w<<<(4 * 32768 + 255) / 256, blk, 0, stream>>>(Wq2, Wk2, Wv2, Ws2, wt2, 256, 128);

  // ================= CSR build =================
  (void)hipMemsetAsync(cnt, 0, (size_t)N * sizeof(int), stream);
  csr_hist<<<egE, blk, 0, stream>>>(ei, E, cnt);
  csr_scan1<<<nch, blk, 0, stream>>>(cnt, rowptr, chks, N);
  csr_scan2<<<1, 64, 0, stream>>>(chks, nch, rowptr, N, E);
  csr_scan3<<<egN, blk, 0, stream>>>(rowptr, chks, N);
  (void)hipMemsetAsync(cnt, 0, (size_t)N * sizeof(int), stream);
  csr_scatter<<<egE, blk, 0, stream>>>(ei, E, rowptr, cnt, csrs);

  // ================= conv1 (K=128, Dout=256) =================
  // q1 f32 -> B0; k1h fp16 -> B1 (reinterp); v1h fp16 -> B2 (reinterp)
  _Float16* k1h = (_Float16*)B1;
  _Float16* v1h = (_Float16*)B2;
  mfma_gemm<128, float>   <<<g1grid, blk, 0, stream>>>(x, wt1 + 0 * 32768, bq1, B0,  N, 256);
  mfma_gemm<128, _Float16><<<g1grid, blk, 0, stream>>>(x, wt1 + 1 * 32768, bk1, k1h, N, 256);
  mfma_gemm<128, _Float16><<<g1grid, blk, 0, stream>>>(x, wt1 + 2 * 32768, bv1, v1h, N, 256);
  attn_fused<256,4><<<ng, blk, 0, stream>>>(rowptr, csrs, B0, k1h, v1h, B0, N); // o over q
  mfma_gemm<128, float>   <<<g1grid, blk, 0, stream>>>(x, wt1 + 3 * 32768, bs1, B1, N, 256); // xr
  node_gate2<256,false><<<ng, blk, 0, stream>>>(B0, B1, Wb1, g1, be1, m1, v1, B2, nullptr, N); // h -> B2

  // ================= conv2 (K=256, Dout=128), input h = B2 =================
  float*    q2p = B0;                               // N*128 f32
  _Float16* k2h = (_Float16*)(B0 + (size_t)N * 128); // N*128 fp16
  _Float16* v2h = (_Float16*)B1;                     // N*128 fp16
  float*    s2p = B1 + (size_t)N * 128;              // N*128 f32
  mfma_gemm<256, float>   <<<g2grid, blk, 0, stream>>>(B2, wt2 + 0 * 32768, bq2, q2p, N, 128);
  mfma_gemm<256, _Float16><<<g2grid, blk, 0, stream>>>(B2, wt2 + 1 * 32768, bk2, k2h, N, 128);
  mfma_gemm<256, _Float16><<<g2grid, blk, 0, stream>>>(B2, wt2 + 2 * 32768, bv2, v2h, N, 128);
  attn_fused<128,4><<<ng, blk, 0, stream>>>(rowptr, csrs, q2p, k2h, v2h, q2p, N);  // o over q2p
  mfma_gemm<256, float>   <<<g2grid, blk, 0, stream>>>(B2, wt2 + 3 * 32768, bs2, s2p, N, 128); // xr
  // z f32 -> B0+N*128 (k2h dead); zh fp16 -> B2 (h dead after s2p gemm)
  float*    z  = B0 + (size_t)N * 128;
  _Float16* zh = (_Float16*)B2;
  node_gate2<128,true><<<ng, blk, 0, stream>>>(q2p, s2p, Wb2, g2, be2, m2, v2, z, zh, N);

  // ================= loss (gathers fp16 zh) =================
  (void)hipMemsetAsync(accbuf, 0, 2 * sizeof(float), stream);
  loss_kernel<<<2048, blk, 0, stream>>>(ei, nei, zh, E, accbuf);

  // ================= conv3 (input z f32), scratch in B1 =================
  float* q3 = B1;
  float* k3 = B1 + (size_t)N;
  float* v3 = B1 + (size_t)2 * N;
  float* s3 = B1 + (size_t)3 * N;
  gemv4<<<ng, blk, 0, stream>>>(z, Wq3, bq3, Wk3, bk3, Wv3, bv3, Ws3, bs3, q3, k3, v3, s3, N);
  attn3_node<<<egN, blk, 0, stream>>>(rowptr, csrs, q3, k3, v3, s3, Wb3, out, N);

  finalize_kernel<<<1, 1, 0, stream>>>(accbuf, c1, c2, out, N, E);
}

// Round 13
// 739.772 us; speedup vs baseline: 2.9124x; 1.0798x over previous
//
#include <hip/hip_runtime.h>
#include <hip/hip_bf16.h>

typedef _Float16 half8 __attribute__((ext_vector_type(8)));
typedef _Float16 half4 __attribute__((ext_vector_type(4)));
typedef _Float16 half2v __attribute__((ext_vector_type(2)));
typedef float f32x4 __attribute__((ext_vector_type(4)));

// ---------- weight prep: W[K][D] f32 -> Wcat[4*D][K] fp16 (q|k|v|s row blocks) ----------
__global__ __launch_bounds__(256) void prep_w(
    const float* __restrict__ W0, const float* __restrict__ W1,
    const float* __restrict__ W2, const float* __restrict__ W3,
    _Float16* __restrict__ T, int K, int D)
{
  int idx = blockIdx.x * 256 + threadIdx.x;
  int tot = K * D;
  if (idx >= 4 * tot) return;
  int which = idx / tot, rem = idx - which * tot;
  int d = rem / K, k = rem - d * K;
  const float* W = which == 0 ? W0 : which == 1 ? W1 : which == 2 ? W2 : W3;
  T[idx] = (_Float16)W[(long long)k * D + d];
}

// ---------- fused 4-projection MFMA GEMM ----------
// Wcat[4*SEGW][K] fp16. Segments: 0->o0 f32 (q), 1->o1 fp16 (k), 2->o2 fp16 (v), 3->o3 f32 (s).
// 64x64 block tile (4 waves 2x2, wave 32x32); each block's cols lie in ONE segment (64|SEGW).
template<int K, int SEGW>
__global__ __launch_bounds__(256) void fused_gemm(
    const float* __restrict__ A, const _Float16* __restrict__ Wcat,
    const float* __restrict__ b0, const float* __restrict__ b1,
    const float* __restrict__ b2, const float* __restrict__ b3,
    float* __restrict__ o0, _Float16* __restrict__ o1,
    _Float16* __restrict__ o2, float* __restrict__ o3, int Nr)
{
  int lane = threadIdx.x & 63;
  int w    = threadIdx.x >> 6;
  int wm = w >> 1, wn = w & 1;
  int row0  = blockIdx.x * 64 + wm * 32;
  int gcol0 = blockIdx.y * 64 + wn * 32;          // global col in [0, 4*SEGW)
  int seg   = (blockIdx.y * 64) / SEGW;           // block-uniform
  int lcol0 = blockIdx.y * 64 - seg * SEGW + wn * 32;
  const float* bias = seg == 0 ? b0 : seg == 1 ? b1 : seg == 2 ? b2 : b3;
  int lr = lane & 15;
  int lk = (lane >> 4) * 8;

  f32x4 acc[2][2] = {};
#pragma unroll
  for (int kb = 0; kb < K; kb += 32) {
    half8 a[2], b[2];
#pragma unroll
    for (int mt = 0; mt < 2; ++mt) {
      int row = row0 + mt * 16 + lr;
      if (row < Nr) {
        const float* p = A + (long long)row * K + kb + lk;
        float4 f0 = *(const float4*)p;
        float4 f1 = *(const float4*)(p + 4);
        a[mt][0] = (_Float16)f0.x; a[mt][1] = (_Float16)f0.y;
        a[mt][2] = (_Float16)f0.z; a[mt][3] = (_Float16)f0.w;
        a[mt][4] = (_Float16)f1.x; a[mt][5] = (_Float16)f1.y;
        a[mt][6] = (_Float16)f1.z; a[mt][7] = (_Float16)f1.w;
      } else {
        a[mt] = half8{};
      }
    }
#pragma unroll
    for (int nt = 0; nt < 2; ++nt) {
      int gc = gcol0 + nt * 16 + lr;
      b[nt] = *(const half8*)(Wcat + (long long)gc * K + kb + lk);
    }
#pragma unroll
    for (int mt = 0; mt < 2; ++mt)
#pragma unroll
      for (int nt = 0; nt < 2; ++nt)
        acc[mt][nt] = __builtin_amdgcn_mfma_f32_16x16x32_f16(a[mt], b[nt], acc[mt][nt], 0, 0, 0);
  }
  // D layout: col=lane&15, row=(lane>>4)*4+i  [m89/m91]
#pragma unroll
  for (int nt = 0; nt < 2; ++nt) {
    int lcol = lcol0 + nt * 16 + lr;
    float bc = bias[lcol];
#pragma unroll
    for (int mt = 0; mt < 2; ++mt) {
      int r0 = row0 + mt * 16 + (lane >> 4) * 4;
#pragma unroll
      for (int i = 0; i < 4; ++i) {
        int row = r0 + i;
        if (row < Nr) {
          float val = acc[mt][nt][i] + bc;
          long long off = (long long)row * SEGW + lcol;
          if      (seg == 0) o0[off] = val;
          else if (seg == 1) o1[off] = (_Float16)val;
          else if (seg == 2) o2[off] = (_Float16)val;
          else               o3[off] = val;
        }
      }
    }
  }
}

// ================= CSR build (dst-indexed), reused by all 3 convs =================
__global__ __launch_bounds__(256) void csr_hist(
    const int* __restrict__ ei, int E, int* __restrict__ cnt)
{
  int e = blockIdx.x * 256 + threadIdx.x;
  if (e >= E) return;
  atomicAdd(&cnt[ei[E + e]], 1);
}

__global__ __launch_bounds__(256) void csr_scan1(
    const int* __restrict__ cnt, int* __restrict__ excl,
    int* __restrict__ chunkSums, int N)
{
  int b = blockIdx.x, t = threadIdx.x;
  int lane = t & 63, w = t >> 6;
  int base = b * 1024 + t * 4;
  int c[4];
#pragma unroll
  for (int j = 0; j < 4; ++j) c[j] = (base + j < N) ? cnt[base + j] : 0;
  int ts = c[0] + c[1] + c[2] + c[3];
  int s = ts;
#pragma unroll
  for (int d = 1; d < 64; d <<= 1) {
    int u = __shfl_up(s, d, 64);
    if (lane >= d) s += u;
  }
  __shared__ int wsum[4];
  if (lane == 63) wsum[w] = s;
  __syncthreads();
  int woff = 0;
  for (int i = 0; i < w; ++i) woff += wsum[i];
  int off = woff + s - ts;
#pragma unroll
  for (int j = 0; j < 4; ++j) {
    if (base + j < N) excl[base + j] = off;
    off += c[j];
  }
  if (t == 0) chunkSums[b] = wsum[0] + wsum[1] + wsum[2] + wsum[3];
}

__global__ void csr_scan2(int* __restrict__ chunkSums, int nch,
                          int* __restrict__ rowptr, int N, int E)
{
  int lane = threadIdx.x;
  int v = (lane < nch) ? chunkSums[lane] : 0;
  int s = v;
#pragma unroll
  for (int d = 1; d < 64; d <<= 1) {
    int u = __shfl_up(s, d, 64);
    if (lane >= d) s += u;
  }
  if (lane < nch) chunkSums[lane] = s - v;
  if (lane == 0) rowptr[N] = E;
}

__global__ __launch_bounds__(256) void csr_scan3(
    int* __restrict__ rowptr, const int* __restrict__ chunkSums, int N)
{
  int i = blockIdx.x * 256 + threadIdx.x;
  if (i < N) rowptr[i] += chunkSums[i >> 10];
}

__global__ __launch_bounds__(256) void csr_scatter(
    const int* __restrict__ ei, int E, const int* __restrict__ rowptr,
    int* __restrict__ fill, int* __restrict__ csr_src)
{
  int e = blockIdx.x * 256 + threadIdx.x;
  if (e >= E) return;
  int s = ei[e], d = ei[E + e];
  int pos = atomicAdd(&fill[d], 1);
  csr_src[rowptr[d] + pos] = s;
}

// ================= fused per-node online-softmax attention (fp16 k/v gathers) =================
template<int D, int H>
__global__ __launch_bounds__(256) void attn_fused(
    const int* __restrict__ rowptr, const int* __restrict__ csr_src,
    const float* __restrict__ q, const _Float16* __restrict__ k,
    const _Float16* __restrict__ v, float* __restrict__ o, int N)
{
  constexpr int PER = D / 64;
  constexpr int DH  = D / H;
  int node = blockIdx.x * 4 + (threadIdx.x >> 6);
  if (node >= N) return;
  int lane = threadIdx.x & 63;
  int j0   = lane * PER;
  const float inv = 1.0f / sqrtf((float)DH);

  float qv[PER];
  if constexpr (PER == 4) {
    float4 t4 = *(const float4*)(q + (long long)node * D + j0);
    qv[0]=t4.x; qv[1]=t4.y; qv[2]=t4.z; qv[3]=t4.w;
  } else {
    float2 t2 = *(const float2*)(q + (long long)node * D + j0);
    qv[0]=t2.x; qv[1]=t2.y;
  }

  float m = -INFINITY, den = 0.f;
  float acc[PER] = {};
  int beg = rowptr[node], end = rowptr[node + 1];
  for (int i = beg; i < end; ++i) {
    int s = csr_src[i];
    float kv[PER], vv[PER];
    if constexpr (PER == 4) {
      half4 t4 = *(const half4*)(k + (long long)s * D + j0);
      half4 u4 = *(const half4*)(v + (long long)s * D + j0);
#pragma unroll
      for (int j = 0; j < 4; ++j) { kv[j] = (float)t4[j]; vv[j] = (float)u4[j]; }
    } else {
      half2v t2 = *(const half2v*)(k + (long long)s * D + j0);
      half2v u2 = *(const half2v*)(v + (long long)s * D + j0);
#pragma unroll
      for (int j = 0; j < 2; ++j) { kv[j] = (float)t2[j]; vv[j] = (float)u2[j]; }
    }
    float dot = 0.f;
#pragma unroll
    for (int j = 0; j < PER; ++j) dot += qv[j] * kv[j];
    dot += __shfl_xor(dot, 8, 64);
    dot += __shfl_xor(dot, 4, 64);
    dot += __shfl_xor(dot, 2, 64);
    dot += __shfl_xor(dot, 1, 64);
    float score = dot * inv;
    float nm = fmaxf(m, score);
    float scale = __expf(m - nm);
    float p = __expf(score - nm);
    den = den * scale + p;
#pragma unroll
    for (int j = 0; j < PER; ++j) acc[j] = acc[j] * scale + p * vv[j];
    m = nm;
  }
  float r = 1.f / (den + 1e-16f);
  if constexpr (PER == 4) {
    float4 w4; w4.x = acc[0]*r; w4.y = acc[1]*r; w4.z = acc[2]*r; w4.w = acc[3]*r;
    *(float4*)(o + (long long)node * D + j0) = w4;
  } else {
    float2 w2; w2.x = acc[0]*r; w2.y = acc[1]*r;
    *(float2*)(o + (long long)node * D + j0) = w2;
  }
}

// ---------- node: beta-gate, BN(eval), ELU; optional fp16 shadow output ----------
template<int D, bool WRITE_H>
__global__ __launch_bounds__(256) void node_gate2(
    const float* __restrict__ o, const float* __restrict__ xr,
    const float* __restrict__ Wb, const float* __restrict__ g,
    const float* __restrict__ be, const float* __restrict__ bm,
    const float* __restrict__ bv, float* __restrict__ out,
    _Float16* __restrict__ outh, int N)
{
  constexpr int PER = D / 64;
  int node = blockIdx.x * 4 + (threadIdx.x >> 6);
  if (node >= N) return;
  int lane = threadIdx.x & 63;
  int j0   = lane * PER;
  float ov[PER], xv[PER];
  if constexpr (PER == 4) {
    float4 o4 = *(const float4*)(o  + (long long)node * D + j0);
    float4 x4 = *(const float4*)(xr + (long long)node * D + j0);
    ov[0]=o4.x; ov[1]=o4.y; ov[2]=o4.z; ov[3]=o4.w;
    xv[0]=x4.x; xv[1]=x4.y; xv[2]=x4.z; xv[3]=x4.w;
  } else {
    float2 o2 = *(const float2*)(o  + (long long)node * D + j0);
    float2 x2 = *(const float2*)(xr + (long long)node * D + j0);
    ov[0]=o2.x; ov[1]=o2.y;
    xv[0]=x2.x; xv[1]=x2.y;
  }
  float dot = 0.f;
#pragma unroll
  for (int i = 0; i < PER; ++i) {
    int j = j0 + i;
    dot += ov[i] * Wb[j] + xv[i] * Wb[D + j] + (ov[i] - xv[i]) * Wb[2 * D + j];
  }
#pragma unroll
  for (int off = 32; off >= 1; off >>= 1) dot += __shfl_xor(dot, off, 64);
  float beta = 1.f / (1.f + expf(-dot));
  float res[PER];
#pragma unroll
  for (int i = 0; i < PER; ++i) {
    int j = j0 + i;
    float h = beta * xv[i] + (1.f - beta) * ov[i];
    float y = (h - bm[j]) * rsqrtf(bv[j] + 1e-5f) * g[j] + be[j];
    res[i] = y > 0.f ? y : expf(y) - 1.f;
  }
  if constexpr (PER == 4) {
    float4 w; w.x=res[0]; w.y=res[1]; w.z=res[2]; w.w=res[3];
    *(float4*)(out + (long long)node * D + j0) = w;
  } else {
    float2 w; w.x=res[0]; w.y=res[1];
    *(float2*)(out + (long long)node * D + j0) = w;
  }
  if constexpr (WRITE_H) {
    if constexpr (PER == 4) {
      half4 hw; hw[0]=(_Float16)res[0]; hw[1]=(_Float16)res[1];
      hw[2]=(_Float16)res[2]; hw[3]=(_Float16)res[3];
      *(half4*)(outh + (long long)node * D + j0) = hw;
    } else {
      half2v hw; hw[0]=(_Float16)res[0]; hw[1]=(_Float16)res[1];
      *(half2v*)(outh + (long long)node * D + j0) = hw;
    }
  }
}

// ---------- loss: one edge per 16-lane group (4 edges/wave in flight) ----------
__global__ __launch_bounds__(256) void loss_kernel(
    const int* __restrict__ ei, const int* __restrict__ nei,
    const _Float16* __restrict__ zh, int E, float* __restrict__ acc)
{
  int lane = threadIdx.x & 63;
  int wib  = threadIdx.x >> 6;
  int sub  = lane >> 4;     // 4 edge-slots per wave
  int r    = lane & 15;     // 16 lanes x half8 = 128 dims
  long long gw = ((long long)blockIdx.x * blockDim.x + threadIdx.x) >> 6;
  long long nw = ((long long)gridDim.x * blockDim.x) >> 6;
  float lpos = 0.f, lneg = 0.f;
  for (long long base = gw * 4; base < 2LL * E; base += nw * 4) {
    long long wq = base + sub;
    if (wq < 2LL * E) {
      int isneg = (wq >= E);
      const int* ep = isneg ? nei : ei;
      long long idx = isneg ? wq - E : wq;
      int s = ep[idx], d = ep[E + idx];
      half8 a = *(const half8*)(zh + (long long)s * 128 + r * 8);
      half8 b = *(const half8*)(zh + (long long)d * 128 + r * 8);
      float dot = 0.f;
#pragma unroll
      for (int j = 0; j < 8; ++j) dot += (float)a[j] * (float)b[j];
      dot += __shfl_xor(dot, 8, 64);
      dot += __shfl_xor(dot, 4, 64);
      dot += __shfl_xor(dot, 2, 64);
      dot += __shfl_xor(dot, 1, 64);
      if (r == 0) {
        float sg = 1.f / (1.f + expf(-dot));
        if (isneg) lneg += -logf(1.f - sg + 1e-15f);
        else       lpos += -logf(sg + 1e-15f);
      }
    }
  }
  // sum the 4 r==0 lanes (0,16,32,48)
  lpos += __shfl_xor(lpos, 16, 64); lpos += __shfl_xor(lpos, 32, 64);
  lneg += __shfl_xor(lneg, 16, 64); lneg += __shfl_xor(lneg, 32, 64);
  __shared__ float sp[4], sn[4];
  if (lane == 0) { sp[wib] = lpos; sn[wib] = lneg; }
  __syncthreads();
  if (threadIdx.x == 0) {
    float P = 0.f, Ng = 0.f;
    for (int i = 0; i < 4; ++i) { P += sp[i]; Ng += sn[i]; }
    atomicAdd(acc, P);
    atomicAdd(acc + 1, Ng);
  }
}

// ---------- conv3: fused 4-way GEMV ----------
__global__ __launch_bounds__(256) void gemv4(
    const float* __restrict__ z,
    const float* __restrict__ Wq, const float* __restrict__ bq,
    const float* __restrict__ Wk, const float* __restrict__ bk,
    const float* __restrict__ Wv, const float* __restrict__ bv,
    const float* __restrict__ Ws, const float* __restrict__ bs,
    float* __restrict__ q3, float* __restrict__ k3,
    float* __restrict__ v3, float* __restrict__ s3, int N)
{
  int node = blockIdx.x * 4 + (threadIdx.x >> 6);
  if (node >= N) return;
  int lane = threadIdx.x & 63;
  float2 zv = *(const float2*)(z + (long long)node * 128 + lane * 2);
  float aq = zv.x * Wq[lane*2] + zv.y * Wq[lane*2+1];
  float ak = zv.x * Wk[lane*2] + zv.y * Wk[lane*2+1];
  float av = zv.x * Wv[lane*2] + zv.y * Wv[lane*2+1];
  float as_ = zv.x * Ws[lane*2] + zv.y * Ws[lane*2+1];
#pragma unroll
  for (int off = 32; off >= 1; off >>= 1) {
    aq  += __shfl_xor(aq,  off, 64);
    ak  += __shfl_xor(ak,  off, 64);
    av  += __shfl_xor(av,  off, 64);
    as_ += __shfl_xor(as_, off, 64);
  }
  if (lane == 0) {
    q3[node] = aq + bq[0];
    k3[node] = ak + bk[0];
    v3[node] = av + bv[0];
    s3[node] = as_ + bs[0];
  }
}

__global__ __launch_bounds__(256) void attn3_node(
    const int* __restrict__ rowptr, const int* __restrict__ csr_src,
    const float* __restrict__ q3, const float* __restrict__ k3,
    const float* __restrict__ v3, const float* __restrict__ s3,
    const float* __restrict__ Wb3, float* __restrict__ out, int N)
{
  int n = blockIdx.x * 256 + threadIdx.x;
  if (n >= N) return;
  float qd = q3[n];
  float m = -INFINITY, den = 0.f, acc = 0.f;
  int beg = rowptr[n], end = rowptr[n + 1];
  for (int i = beg; i < end; ++i) {
    int s = csr_src[i];
    float sc = qd * k3[s];
    float nm = fmaxf(m, sc);
    float scale = __expf(m - nm);
    float p = __expf(sc - nm);
    den = den * scale + p;
    acc = acc * scale + p * v3[s];
    m = nm;
  }
  float on = acc / (den + 1e-16f);
  float xr = s3[n];
  float tv = on * Wb3[0] + xr * Wb3[1] + (on - xr) * Wb3[2];
  float b = 1.f / (1.f + expf(-tv));
  out[n] = b * xr + (1.f - b) * on;
}

__global__ void finalize_kernel(const float* __restrict__ acc,
                                const float* __restrict__ c1, const float* __restrict__ c2,
                                float* __restrict__ out, int N, int E)
{
  out[N]     = acc[0] / (float)E + acc[1] / (float)E;
  out[N + 1] = c1[0];
  out[N + 2] = c2[0];
}

// ---------- orchestration ----------
extern "C" void kernel_launch(void* const* d_in, const int* in_sizes, int n_in,
                              void* d_out, int out_size, void* d_ws, size_t ws_size,
                              hipStream_t stream)
{
  const float* x   = (const float*)d_in[0];
  const int*   ei  = (const int*)d_in[1];
  const int*   nei = (const int*)d_in[2];
  const float* Wq1 = (const float*)d_in[3];  const float* bq1 = (const float*)d_in[4];
  const float* Wk1 = (const float*)d_in[5];  const float* bk1 = (const float*)d_in[6];
  const float* Wv1 = (const float*)d_in[7];  const float* bv1 = (const float*)d_in[8];
  const float* Ws1 = (const float*)d_in[9];  const float* bs1 = (const float*)d_in[10];
  const float* Wb1 = (const float*)d_in[11];
  const float* g1  = (const float*)d_in[12]; const float* be1 = (const float*)d_in[13];
  const float* m1  = (const float*)d_in[14]; const float* v1  = (const float*)d_in[15];
  const float* Wq2 = (const float*)d_in[16]; const float* bq2 = (const float*)d_in[17];
  const float* Wk2 = (const float*)d_in[18]; const float* bk2 = (const float*)d_in[19];
  const float* Wv2 = (const float*)d_in[20]; const float* bv2 = (const float*)d_in[21];
  const float* Ws2 = (const float*)d_in[22]; const float* bs2 = (const float*)d_in[23];
  const float* Wb2 = (const float*)d_in[24];
  const float* g2  = (const float*)d_in[25]; const float* be2 = (const float*)d_in[26];
  const float* m2  = (const float*)d_in[27]; const float* v2  = (const float*)d_in[28];
  const float* Wq3 = (const float*)d_in[29]; const float* bq3 = (const float*)d_in[30];
  const float* Wk3 = (const float*)d_in[31]; const float* bk3 = (const float*)d_in[32];
  const float* Wv3 = (const float*)d_in[33]; const float* bv3 = (const float*)d_in[34];
  const float* Ws3 = (const float*)d_in[35]; const float* bs3 = (const float*)d_in[36];
  const float* Wb3 = (const float*)d_in[37];
  const float* c1  = (const float*)d_in[38]; const float* c2  = (const float*)d_in[39];

  const int N = in_sizes[0] / 128;   // 50000
  const int E = in_sizes[1] / 2;     // 250000

  float* ws = (float*)d_ws;
  float* B0 = ws;                        // N*256 f32
  float* B1 = B0 + (size_t)N * 256;      // N*256 f32
  float* B2 = B1 + (size_t)N * 256;      // N*256 f32
  int* rowptr = (int*)(B2 + (size_t)N * 256);  // N+1
  int* cnt    = rowptr + (N + 1);              // N (also fill)
  int* csrs   = cnt + N;                       // E
  int* chks   = csrs + E;                      // 64
  float* accbuf = (float*)(chks + 64);         // 2
  uintptr_t wp = ((uintptr_t)(accbuf + 2) + 63) & ~(uintptr_t)63;
  _Float16* wt1 = (_Float16*)wp;               // 4 * 128*256  (= Wcat1[1024][128])
  _Float16* wt2 = wt1 + 4 * 32768;             // 4 * 256*128  (= Wcat2[512][256])

  size_t need = ((size_t)3 * N * 256) * 4 + ((size_t)2 * N + 1 + E + 64) * 4 + 8
              + 64 + 8 * 32768 * sizeof(_Float16);
  if (ws_size < need) return;

  float* out = (float*)d_out;
  dim3 blk(256);
  int ng  = (N + 3) / 4;
  int egE = (E + 255) / 256;
  int egN = (N + 255) / 256;
  int nch = (N + 1023) / 1024;    // 49 (<= 64)
  dim3 fg1((N + 63) / 64, 1024 / 64);   // conv1 fused: Dout_total=1024
  dim3 fg2((N + 63) / 64, 512 / 64);    // conv2 fused: Dout_total=512

  // ================= weight prep (Wcat fp16) =================
  prep_w<<<(4 * 32768 + 255) / 256, blk, 0, stream>>>(Wq1, Wk1, Wv1, Ws1, wt1, 128, 256);
  prep_w<<<(4 * 32768 + 255) / 256, blk, 0, stream>>>(Wq2, Wk2, Wv2, Ws2, wt2, 256, 128);

  // ================= CSR build =================
  (void)hipMemsetAsync(cnt, 0, (size_t)N * sizeof(int), stream);
  csr_hist<<<egE, blk, 0, stream>>>(ei, E, cnt);
  csr_scan1<<<nch, blk, 0, stream>>>(cnt, rowptr, chks, N);
  csr_scan2<<<1, 64, 0, stream>>>(chks, nch, rowptr, N, E);
  csr_scan3<<<egN, blk, 0, stream>>>(rowptr, chks, N);
  (void)hipMemsetAsync(cnt, 0, (size_t)N * sizeof(int), stream);
  csr_scatter<<<egE, blk, 0, stream>>>(ei, E, rowptr, cnt, csrs);

  // ================= conv1 (K=128, SEGW=256) =================
  // q f32 -> B0 | k fp16 -> B1 lo | v fp16 -> B1 hi | s f32 -> B2
  _Float16* k1h = (_Float16*)B1;
  _Float16* v1h = k1h + (size_t)N * 256;
  fused_gemm<128,256><<<fg1, blk, 0, stream>>>(x, wt1, bq1, bk1, bv1, bs1,
                                               B0, k1h, v1h, B2, N);
  attn_fused<256,4><<<ng, blk, 0, stream>>>(rowptr, csrs, B0, k1h, v1h, B0, N); // o over q
  node_gate2<256,false><<<ng, blk, 0, stream>>>(B0, B2, Wb1, g1, be1, m1, v1, B1, nullptr, N); // h -> B1

  // ================= conv2 (K=256, SEGW=128), input h = B1 =================
  // q f32 -> B0 lo | k fp16 -> B0 hi lo | v fp16 -> B0 hi hi | s f32 -> B2 lo
  float*    q2p = B0;
  _Float16* k2h = (_Float16*)(B0 + (size_t)N * 128);
  _Float16* v2h = k2h + (size_t)N * 128;
  float*    s2p = B2;
  fused_gemm<256,128><<<fg2, blk, 0, stream>>>(B1, wt2, bq2, bk2, bv2, bs2,
                                               q2p, k2h, v2h, s2p, N);
  attn_fused<128,4><<<ng, blk, 0, stream>>>(rowptr, csrs, q2p, k2h, v2h, q2p, N); // o over q2p
  // z f32 -> B1 lo (h dead); zh fp16 -> B2 + N*128 (s2p region untouched)
  float*    z  = B1;
  _Float16* zh = (_Float16*)(B2 + (size_t)N * 128);
  node_gate2<128,true><<<ng, blk, 0, stream>>>(q2p, s2p, Wb2, g2, be2, m2, v2, z, zh, N);

  // ================= loss (fp16 zh, 16-lane edges) =================
  (void)hipMemsetAsync(accbuf, 0, 2 * sizeof(float), stream);
  loss_kernel<<<2048, blk, 0, stream>>>(ei, nei, zh, E, accbuf);

  // ================= conv3 (input z = B1 lo), scratch in B2 lo (s2p dead) =================
  float* q3 = B2;
  float* k3 = B2 + (size_t)N;
  float* v3 = B2 + (size_t)2 * N;
  float* s3 = B2 + (size_t)3 * N;
  gemv4<<<ng, blk, 0, stream>>>(z, Wq3, bq3, Wk3, bk3, Wv3, bv3, Ws3, bs3, q3, k3, v3, s3, N);
  attn3_node<<<egN, blk, 0, stream>>>(rowptr, csrs, q3, k3, v3, s3, Wb3, out, N);

  finalize_kernel<<<1, 1, 0, stream>>>(accbuf, c1, c2, out, N, E);
}